// Round 16
// baseline (6704.105 us; speedup 1.0000x reference)
//
#include <hip/hip_runtime.h>
#include <hip/hip_bf16.h>

// FP32-intermediate pipeline; R14 split-bf16 MFMA GEMM; R18 dual-n
// fallbacks; R19 gemmM 128x64/BK=64; R24 no scatter writes + k_trsp
// (5764us, passed).
// R25-R29: FIVE identical zero-output failures (absmax 2.4648 = max|ref|),
// incl. byte-equivalent previously-passing source (R27) and a no-d_ws
// statics variant using hipGetSymbolAddress (R29). Harness doesn't check
// launch errors -> any failed launch chain leaves pre-memset zeros.
// R30: remove ALL remaining attack surfaces:
//  (a) zero HIP runtime API calls in kernel_launch (no d_ws, no
//      hipGetSymbolAddress) — kernels reference ~97MB of module-scope
//      __device__ statics DIRECTLY via int/template selectors;
//  (b) inputs identified by in_sizes (unique element counts; x1/x2/x4
//      scales), positional fallback -> robust to input reordering;
//  (c) premerge tier dropped (smaller statics; fallbacks for all roles).
// Kernel bodies are the R24-verified ones verbatim.

#define B_    16
#define T_    12
#define N_    2048
#define HID_  64
#define ED_   10
#define HOR_  12
#define BH    (B_*HID_)    // 1024
#define BT    (B_*T_)      // 192
#define SL_   (N_*BH)      // 2097152

typedef __hip_bfloat16 bf16;
typedef __attribute__((ext_vector_type(8))) short short8;
typedef __attribute__((ext_vector_type(4))) float floatx4;

// ---------------------------------------------------------------------------
// Module-scope static buffers (~97MB). Referenced directly in device code.
// ---------------------------------------------------------------------------
__device__ int            g_flag[64];
__device__ float          g_Ein[N_*ED_];
__device__ float          g_cwf[HOR_*HID_];
__device__ float          g_cbf[HOR_ + 4];
__device__ unsigned short g_Shi[N_*N_];
__device__ unsigned short g_Slo[N_*N_];
__device__ float          g_Wg0F[ED_*128*160];
__device__ float          g_Wu0F[ED_*64*160];
__device__ float          g_Wg1F[ED_*128*256];
__device__ float          g_Wu1F[ED_*64*256];
__device__ unsigned short g_Wg0H[ED_*128*160];
__device__ unsigned short g_Wu0H[ED_*64*160];
__device__ unsigned short g_Wg1H[ED_*128*256];
__device__ unsigned short g_Wu1H[ED_*64*256];
__device__ float          g_bgv0[N_*128];
__device__ float          g_buv0[N_*64];
__device__ float          g_bgv1[N_*128];
__device__ float          g_buv1[N_*64];
__device__ float          g_srcf[BT*N_];
__device__ unsigned short g_srcHi[BT*N_];
__device__ unsigned short g_srcLo[BT*N_];
__device__ float          g_Sx0[N_*BT];
__device__ float          g_h[2*SL_];        // h0 | h2
__device__ float          g_Sh[2*SL_];       // Sh_a | Sh_b
__device__ float          g_zh[SL_];
__device__ float          g_rbuf[SL_];
__device__ unsigned short g_tmpTh[SL_];
__device__ unsigned short g_tmpTl[SL_];
__device__ unsigned short g_h2Th[SL_];
__device__ unsigned short g_h2Tl[SL_];

__device__ __forceinline__ float b2f(bf16 x){ return __bfloat162float(x); }
__device__ __forceinline__ bf16  f2b(float x){ return __float2bfloat16(x); }
__device__ __forceinline__ float bits2f(unsigned u) {
  union { float f; unsigned i; } c; c.i = u << 16; return c.f;
}
__device__ __forceinline__ float ldin(const void* p, size_t i, int isbf) {
  return isbf ? b2f(((const bf16*)p)[i]) : ((const float*)p)[i];
}
__device__ __forceinline__ void fma4(float4& a, float s, const float4& b) {
  a.x += s*b.x; a.y += s*b.y; a.z += s*b.z; a.w += s*b.w;
}

// ---------------------------------------------------------------------------
// dtype detector on E
// ---------------------------------------------------------------------------
__global__ void k_detect(const void* __restrict__ E) {
  __shared__ int cnt;
  if (threadIdx.x == 0) cnt = 0;
  __syncthreads();
  const unsigned* w = (const unsigned*)E;
  int c = 0;
  for (int i = threadIdx.x; i < 4096; i += 256) {
    const unsigned e = (w[i] >> 7) & 0xFFu;
    if (e >= 0x6Eu && e <= 0x86u) ++c;
  }
  atomicAdd(&cnt, c);
  __syncthreads();
  if (threadIdx.x == 0) g_flag[0] = (cnt > 2048) ? 1 : 0;
}

// --- input casts to fp32 internal buffers ---
__global__ void k_castE(const void* __restrict__ E) {
  const int i = blockIdx.x*256 + threadIdx.x;
  if (i < N_*ED_) g_Ein[i] = ldin(E, i, g_flag[0]);
}
__global__ void k_castsrc(const void* __restrict__ src) {
  const int i = blockIdx.x*256 + threadIdx.x;
  if (i < B_*T_*N_) g_srcf[i] = ldin(src, i, g_flag[0]);
}
__global__ void k_castc(const void* __restrict__ cw, const void* __restrict__ cb) {
  const int i = blockIdx.x*256 + threadIdx.x;
  const int f = g_flag[0];
  if (i < HOR_*HID_) g_cwf[i] = ldin(cw, i, f);
  if (i < HOR_)      g_cbf[i] = ldin(cb, i, f);
}

// ---------------------------------------------------------------------------
// S = softmax(relu(Ein @ Ein^T), axis=1) -> hi/lo bf16 pair directly.
// ---------------------------------------------------------------------------
__global__ __launch_bounds__(256) void k_softmax_S() {
  bf16* Sh = (bf16*)g_Shi;
  bf16* Sl = (bf16*)g_Slo;
  const int n = blockIdx.x, tid = threadIdx.x;
  __shared__ float er[ED_];
  __shared__ float red[4];
  if (tid < ED_) er[tid] = g_Ein[n*ED_ + tid];
  __syncthreads();
  float e[ED_];
#pragma unroll
  for (int d = 0; d < ED_; ++d) e[d] = er[d];
  float v[8];
  float mx = 0.f;
#pragma unroll
  for (int j = 0; j < 8; ++j) {
    const int m = tid + j*256;
    float dot = 0.f;
#pragma unroll
    for (int d = 0; d < ED_; ++d) dot += e[d]*g_Ein[m*ED_ + d];
    v[j] = fmaxf(dot, 0.f);
    mx = fmaxf(mx, v[j]);
  }
  for (int o = 32; o; o >>= 1) mx = fmaxf(mx, __shfl_xor(mx, o, 64));
  if ((tid & 63) == 0) red[tid >> 6] = mx;
  __syncthreads();
  mx = fmaxf(fmaxf(red[0], red[1]), fmaxf(red[2], red[3]));
  __syncthreads();
  float sum = 0.f;
#pragma unroll
  for (int j = 0; j < 8; ++j) { v[j] = __expf(v[j] - mx); sum += v[j]; }
  for (int o = 32; o; o >>= 1) sum += __shfl_xor(sum, o, 64);
  if ((tid & 63) == 0) red[tid >> 6] = sum;
  __syncthreads();
  sum = red[0] + red[1] + red[2] + red[3];
  const float inv = 1.f / sum;
#pragma unroll
  for (int j = 0; j < 8; ++j) {
    const float sv = v[j]*inv;
    const size_t idx = (size_t)n*N_ + tid + j*256;
    const bf16 h = f2b(sv);
    Sh[idx] = h;
    Sl[idx] = f2b(sv - b2f(h));
  }
}

// split srcf -> hi/lo bf16 pair
__global__ void k_splitSrc() {
  const int i = blockIdx.x*256 + threadIdx.x;
  if (i < BT*N_) {
    const float v = g_srcf[i];
    const bf16 h = f2b(v);
    ((bf16*)g_srcHi)[i] = h;
    ((bf16*)g_srcLo)[i] = f2b(v - b2f(h));
  }
}

// ---------------------------------------------------------------------------
// Tiled transpose+split: X[n][BH] fp32 -> Th[c][N_], Tl[c][N_] bf16.
// xsel: 0=h0, 1=h2, 2=zh. dsel: 0=tmpT, 1=h2T.
// ---------------------------------------------------------------------------
__global__ __launch_bounds__(256) void k_trsp(int xsel, int dsel) {
  const float* X = (xsel == 0) ? g_h : (xsel == 1) ? (g_h + SL_) : g_zh;
  bf16* Th = (bf16*)((dsel == 0) ? g_tmpTh : g_h2Th);
  bf16* Tl = (bf16*)((dsel == 0) ? g_tmpTl : g_h2Tl);
  const int n0 = blockIdx.x * 64;
  const int c0 = blockIdx.y * 64;
  __shared__ float t[64][68];
  const int tid = threadIdx.x;
  {
    const int r = tid >> 2, q4 = (tid & 3) * 16;
    const float4* src = (const float4*)(X + (size_t)(n0 + r)*BH + c0 + q4);
#pragma unroll
    for (int u = 0; u < 4; ++u)
      *(float4*)&t[r][q4 + u*4] = src[u];
  }
  __syncthreads();
  {
    const int c = tid >> 2, sg = (tid & 3) * 16;
    bf16 hb[16], lb[16];
#pragma unroll
    for (int i = 0; i < 16; ++i) {
      const float v = t[sg + i][c];
      const bf16 h = f2b(v);
      hb[i] = h;
      lb[i] = f2b(v - b2f(h));
    }
    bf16* dh = Th + (size_t)(c0 + c)*N_ + n0 + sg;
    bf16* dl = Tl + (size_t)(c0 + c)*N_ + n0 + sg;
    *(uint4*)dh       = *(uint4*)&hb[0];
    *(uint4*)(dh + 8) = *(uint4*)&hb[8];
    *(uint4*)dl       = *(uint4*)&lb[0];
    *(uint4*)(dl + 8) = *(uint4*)&lb[8];
  }
}

// ---------------------------------------------------------------------------
// Basis weights -> PACKED d-interleaved layout, fp32 + bf16.
// wsel: 0=Wg0, 1=Wu0, 2=Wg1, 3=Wu1.
// ---------------------------------------------------------------------------
template<int LAYER>
__global__ __launch_bounds__(256) void k_prepP(const void* __restrict__ Wb,
                                               int KIin, int KIP, int O,
                                               int wsel) {
  float* PF = (wsel == 0) ? g_Wg0F : (wsel == 1) ? g_Wu0F
            : (wsel == 2) ? g_Wg1F : g_Wu1F;
  bf16* PH = (bf16*)((wsel == 0) ? g_Wg0H : (wsel == 1) ? g_Wu0H
            : (wsel == 2) ? g_Wg1H : g_Wu1H);
  const int idx = blockIdx.x*256 + threadIdx.x;
  if (idx >= ED_*O*KIP) return;
  const int d = idx / (O*KIP), rem = idx - d*O*KIP;
  const int o = rem / KIP, kp = rem - o*KIP;
  int cheb, i; bool valid;
  if (LAYER == 0) {
    cheb = (kp >= 80) ? 1 : 0;
    const int local = kp - cheb*80;
    if (local < 64)       { i = local + 1; valid = true; }
    else if (local == 64) { i = 0;         valid = true; }
    else                  { i = 0;         valid = false; }
  } else {
    cheb = kp >> 7; i = kp & 127; valid = true;
  }
  float v = 0.f;
  if (valid) v = ldin(Wb, (size_t)((d*2 + cheb)*KIin + i)*O + o, g_flag[0]);
  const int kg = kp >> 2, e = kp & 3;
  const size_t pi = ((size_t)(o*(KIP/4) + kg)*ED_ + d)*4 + e;
  PF[pi] = v;
  PH[pi] = f2b(v);
}

// bias vectors: outv[n][o] = sum_d Ein[n,d]*bb[d][o]
// osel: 0=bgv0, 1=buv0, 2=bgv1, 3=buv1.
__global__ __launch_bounds__(128) void k_matb(const void* __restrict__ bb,
                                              int O, int osel) {
  float* outv = (osel == 0) ? g_bgv0 : (osel == 1) ? g_buv0
              : (osel == 2) ? g_bgv1 : g_buv1;
  const int n = blockIdx.x, tid = threadIdx.x;
  if (tid >= O) return;
  const int f = g_flag[0];
  float acc = 0.f;
#pragma unroll
  for (int d = 0; d < ED_; ++d) acc += g_Ein[n*ED_ + d]*ldin(bb, d*O + tid, f);
  outv[n*O + tid] = acc;
}

// ---------------------------------------------------------------------------
// Split-bf16 MFMA GEMM (R19): C(n,c) = sum_m S[n,m]*X[m,c]. 128x64 tile,
// BK=64, LDS stride 72 bf16, 4 waves each 64x32.
// xsel: 0=tmpT, 1=h2T, 2=srcT. csel: 0=Sh_a, 1=Sh_b, 2=Sx0.
// ---------------------------------------------------------------------------
__global__ __launch_bounds__(256) void k_gemmM(int x1, int c1, int ldc1,
                                               int x2, int c2, int ldc2,
                                               int split) {
  const bf16* Sh = (const bf16*)g_Shi;
  const bf16* Sl = (const bf16*)g_Slo;
  const int bm = blockIdx.x * 128;
  int bc = blockIdx.y * 64;
  int xs = x1, cs = c1, ldc = ldc1;
  if (bc >= split) { xs = x2; cs = c2; ldc = ldc2; bc -= split; }
  const bf16* Xh = (const bf16*)((xs == 0) ? g_tmpTh : (xs == 1) ? g_h2Th : g_srcHi);
  const bf16* Xl = (const bf16*)((xs == 0) ? g_tmpTl : (xs == 1) ? g_h2Tl : g_srcLo);
  float* C = (cs == 0) ? g_Sh : (cs == 1) ? (g_Sh + SL_) : g_Sx0;

  __shared__ __align__(16) bf16 Ah[128][72];
  __shared__ __align__(16) bf16 Al[128][72];
  __shared__ __align__(16) bf16 Bh[64][72];
  __shared__ __align__(16) bf16 Bl[64][72];
  const int tid = threadIdx.x;
  const int wave = tid >> 6, lane = tid & 63, q = lane >> 4, ln = lane & 15;
  const int wm = wave >> 1, wn = wave & 1;
  const int srow = tid >> 3, scol = (tid & 7) * 8;

  floatx4 acc[4][2];
#pragma unroll
  for (int mt = 0; mt < 4; ++mt)
#pragma unroll
    for (int nt = 0; nt < 2; ++nt) acc[mt][nt] = (floatx4){0.f,0.f,0.f,0.f};

  for (int mk = 0; mk < N_; mk += 64) {
#pragma unroll
    for (int i = 0; i < 4; ++i) {
      const int r = i*32 + srow;
      *(uint4*)&Ah[r][scol] = *(const uint4*)(Sh + (size_t)(bm + r)*N_ + mk + scol);
      *(uint4*)&Al[r][scol] = *(const uint4*)(Sl + (size_t)(bm + r)*N_ + mk + scol);
    }
#pragma unroll
    for (int i = 0; i < 2; ++i) {
      const int r = i*32 + srow;
      *(uint4*)&Bh[r][scol] = *(const uint4*)(Xh + (size_t)(bc + r)*N_ + mk + scol);
      *(uint4*)&Bl[r][scol] = *(const uint4*)(Xl + (size_t)(bc + r)*N_ + mk + scol);
    }
    __syncthreads();
#pragma unroll
    for (int ks = 0; ks < 64; ks += 32) {
      short8 ah[4], al[4], bh[2], bl[2];
#pragma unroll
      for (int mt = 0; mt < 4; ++mt) {
        ah[mt] = *(const short8*)&Ah[wm*64 + mt*16 + ln][ks + q*8];
        al[mt] = *(const short8*)&Al[wm*64 + mt*16 + ln][ks + q*8];
      }
#pragma unroll
      for (int nt = 0; nt < 2; ++nt) {
        bh[nt] = *(const short8*)&Bh[wn*32 + nt*16 + ln][ks + q*8];
        bl[nt] = *(const short8*)&Bl[wn*32 + nt*16 + ln][ks + q*8];
      }
#pragma unroll
      for (int mt = 0; mt < 4; ++mt)
#pragma unroll
        for (int nt = 0; nt < 2; ++nt) {
          acc[mt][nt] = __builtin_amdgcn_mfma_f32_16x16x32_bf16(ah[mt], bh[nt], acc[mt][nt], 0, 0, 0);
          acc[mt][nt] = __builtin_amdgcn_mfma_f32_16x16x32_bf16(al[mt], bh[nt], acc[mt][nt], 0, 0, 0);
          acc[mt][nt] = __builtin_amdgcn_mfma_f32_16x16x32_bf16(ah[mt], bl[nt], acc[mt][nt], 0, 0, 0);
        }
    }
    __syncthreads();
  }
#pragma unroll
  for (int mt = 0; mt < 4; ++mt)
#pragma unroll
    for (int nt = 0; nt < 2; ++nt)
#pragma unroll
      for (int r = 0; r < 4; ++r)
        C[(size_t)(bm + wm*64 + mt*16 + q*4 + r)*ldc + bc + wn*32 + nt*16 + ln] =
            acc[mt][nt][r];
}

// ---------------------------------------------------------------------------
// xg builder (float4): xg[b][k], padded row stride KIPP (R13 verbatim).
// ---------------------------------------------------------------------------
template<int LAYER, int KIP, int KIPP>
__device__ __forceinline__ void build4(float (*xg)[KIPP],
                                       const float* p0, const float* p1,
                                       const float* p2, const float* p3,
                                       int n, int t, int tid) {
  constexpr int NQ = KIP/4;
  for (int idx = tid; idx < B_*NQ; idx += 256) {
    const int b = idx / NQ, k = (idx - b*NQ) * 4;
    float4 v = make_float4(0.f, 0.f, 0.f, 0.f);
    if (LAYER == 1) {
      const float* rg = (k < 64) ? p0 : (k < 128) ? p1 : (k < 192) ? p2 : p3;
      v = *(const float4*)(rg + (size_t)n*BH + b*64 + (k & 63));
    } else {
      if (k < 64)        v = *(const float4*)(p0 + (size_t)n*BH + b*64 + k);
      else if (k == 64)  v.x = p1[(size_t)(b*T_ + t)*N_ + n];
      else if (k >= 80 && k < 144)
                         v = *(const float4*)(p2 + (size_t)n*BH + b*64 + (k - 80));
      else if (k == 144) v.x = p3[(size_t)n*BT + b*T_ + t];
    }
    *(float4*)&xg[b][k] = v;
  }
}

// R18: dual-n merge — one basis load feeds both n's accumulators.
template<int KIP>
__device__ __forceinline__ void merge_p2(const float* __restrict__ PF,
                                         const bf16* __restrict__ PH,
                                         const float* el0, const float* el1,
                                         int o, int kg, int isbf,
                                         float4& a0, float4& a1) {
  const size_t gbase = (size_t)(o*(KIP/4) + kg)*(ED_*4);
  if (isbf) {
    const uint4* g = (const uint4*)(PH + gbase);
#pragma unroll
    for (int i = 0; i < 5; ++i) {
      const uint4 w = g[i];
      const float f0 = bits2f(w.x & 0xFFFFu), f1 = bits2f(w.x >> 16);
      const float f2 = bits2f(w.y & 0xFFFFu), f3 = bits2f(w.y >> 16);
      const float f4 = bits2f(w.z & 0xFFFFu), f5 = bits2f(w.z >> 16);
      const float f6 = bits2f(w.w & 0xFFFFu), f7 = bits2f(w.w >> 16);
      const float e00 = el0[2*i], e01 = el0[2*i + 1];
      const float e10 = el1[2*i], e11 = el1[2*i + 1];
      a0.x += e00*f0; a0.y += e00*f1; a0.z += e00*f2; a0.w += e00*f3;
      a0.x += e01*f4; a0.y += e01*f5; a0.z += e01*f6; a0.w += e01*f7;
      a1.x += e10*f0; a1.y += e10*f1; a1.z += e10*f2; a1.w += e10*f3;
      a1.x += e11*f4; a1.y += e11*f5; a1.z += e11*f6; a1.w += e11*f7;
    }
  } else {
    const float4* g = (const float4*)(PF + gbase);
#pragma unroll
    for (int d = 0; d < ED_; ++d) {
      const float4 w = g[d];
      fma4(a0, el0[d], w);
      fma4(a1, el1[d], w);
    }
  }
}

// ---------------------------------------------------------------------------
// Gate fallback, TWO n per block, FULL upfront xg, no transposed writes.
// All buffer pointers derived from LAYER inside the kernel.
// ---------------------------------------------------------------------------
template<int LAYER, int KIP>
__global__ __launch_bounds__(256, 2) void k_gateW2(int t) {
  constexpr int KIPP = KIP + 4;
  constexpr int O = 128;
  const float* PF = (LAYER == 0) ? g_Wg0F : g_Wg1F;
  const bf16*  PH = (const bf16*)((LAYER == 0) ? g_Wg0H : g_Wg1H);
  const float* bgv = (LAYER == 0) ? g_bgv0 : g_bgv1;
  const float* p0 = g_h;
  const float* p1 = (LAYER == 0) ? g_srcf : (g_h + SL_);
  const float* p2 = g_Sh;
  const float* p3 = (LAYER == 0) ? g_Sx0 : (g_Sh + SL_);
  const float* hstate = (LAYER == 0) ? g_h : (g_h + SL_);
  const int n0 = blockIdx.x, n1 = blockIdx.x + N_/2, tid = threadIdx.x;
  __shared__ float xg[2][B_][KIPP];
  __shared__ float wm[2][O][36];
  __shared__ float es[2][ED_];
  if (tid < ED_) es[0][tid] = g_Ein[n0*ED_ + tid];
  if (tid >= 32 && tid < 32 + ED_) es[1][tid - 32] = g_Ein[n1*ED_ + (tid - 32)];
  build4<LAYER, KIP, KIPP>(xg[0], p0, p1, p2, p3, n0, t, tid);
  build4<LAYER, KIP, KIPP>(xg[1], p0, p1, p2, p3, n1, t, tid);
  __syncthreads();
  const int isbf = g_flag[0];
  float el0[ED_], el1[ED_];
#pragma unroll
  for (int d = 0; d < ED_; ++d) { el0[d] = es[0][d]; el1[d] = es[1][d]; }

  const int b = tid >> 4, q = tid & 15;
  float ac0[8], ac1[8];
#pragma unroll
  for (int j = 0; j < 8; ++j) { ac0[j] = 0.f; ac1[j] = 0.f; }

  for (int k0 = 0; k0 < KIP; k0 += 32) {
#pragma unroll
    for (int i = 0; i < O*8/256; ++i) {
      const int idx = tid + i*256;
      const int o = idx >> 3, kq = idx & 7;
      float4 a0 = make_float4(0.f, 0.f, 0.f, 0.f);
      float4 a1 = make_float4(0.f, 0.f, 0.f, 0.f);
      merge_p2<KIP>(PF, PH, el0, el1, o, (k0 >> 2) + kq, isbf, a0, a1);
      *(float4*)&wm[0][o][kq*4] = a0;
      *(float4*)&wm[1][o][kq*4] = a1;
    }
    __syncthreads();
#pragma unroll
    for (int kq = 0; kq < 8; ++kq) {
      const float4 xv0 = *(const float4*)&xg[0][b][k0 + kq*4];
      const float4 xv1 = *(const float4*)&xg[1][b][k0 + kq*4];
#pragma unroll
      for (int j = 0; j < 8; ++j) {
        const float4 w0 = *(const float4*)&wm[0][q + 16*j][kq*4];
        const float4 w1 = *(const float4*)&wm[1][q + 16*j][kq*4];
        ac0[j] += xv0.x*w0.x + xv0.y*w0.y + xv0.z*w0.z + xv0.w*w0.w;
        ac1[j] += xv1.x*w1.x + xv1.y*w1.y + xv1.z*w1.z + xv1.w*w1.w;
      }
    }
    __syncthreads();
  }
#pragma unroll
  for (int j = 0; j < 8; ++j) {
    const int o = q + 16*j;
    {
      float s = ac0[j] + bgv[n0*128 + o];
      s = 1.f/(1.f + __expf(-s));
      if (o < HID_) {
        g_zh[(size_t)n0*BH + b*64 + o] = s*hstate[(size_t)n0*BH + b*64 + o];
      } else {
        g_rbuf[(size_t)n0*BH + b*64 + (o - HID_)] = s;
      }
    }
    {
      float s = ac1[j] + bgv[n1*128 + o];
      s = 1.f/(1.f + __expf(-s));
      if (o < HID_) {
        g_zh[(size_t)n1*BH + b*64 + o] = s*hstate[(size_t)n1*BH + b*64 + o];
      } else {
        g_rbuf[(size_t)n1*BH + b*64 + (o - HID_)] = s;
      }
    }
  }
}

// ---------------------------------------------------------------------------
// Candidate fallback, TWO n per block, FULL upfront xg, no transposed writes.
// ---------------------------------------------------------------------------
template<int LAYER, int KIP>
__global__ __launch_bounds__(256, 2) void k_candW2f(int t) {
  constexpr int KIPP = KIP + 4;
  constexpr int O = 64;
  const float* PF = (LAYER == 0) ? g_Wu0F : g_Wu1F;
  const bf16*  PH = (const bf16*)((LAYER == 0) ? g_Wu0H : g_Wu1H);
  const float* buv = (LAYER == 0) ? g_buv0 : g_buv1;
  const float* p0 = (LAYER == 0) ? g_zh : g_h;
  const float* p1 = (LAYER == 0) ? g_srcf : g_zh;
  const float* p2 = (LAYER == 0) ? (g_Sh + SL_) : g_Sh;
  const float* p3 = (LAYER == 0) ? g_Sx0 : (g_Sh + SL_);
  float* hstate = (LAYER == 0) ? g_h : (g_h + SL_);
  const int n0 = blockIdx.x, n1 = blockIdx.x + N_/2, tid = threadIdx.x;
  __shared__ float xg[2][B_][KIPP];
  __shared__ float wm[2][O][36];
  __shared__ float es[2][ED_];
  if (tid < ED_) es[0][tid] = g_Ein[n0*ED_ + tid];
  if (tid >= 32 && tid < 32 + ED_) es[1][tid - 32] = g_Ein[n1*ED_ + (tid - 32)];
  build4<LAYER, KIP, KIPP>(xg[0], p0, p1, p2, p3, n0, t, tid);
  build4<LAYER, KIP, KIPP>(xg[1], p0, p1, p2, p3, n1, t, tid);
  __syncthreads();
  const int isbf = g_flag[0];
  float el0[ED_], el1[ED_];
#pragma unroll
  for (int d = 0; d < ED_; ++d) { el0[d] = es[0][d]; el1[d] = es[1][d]; }

  const int b = tid >> 4, q = tid & 15;
  float ac0[4], ac1[4];
#pragma unroll
  for (int j = 0; j < 4; ++j) { ac0[j] = 0.f; ac1[j] = 0.f; }

  for (int k0 = 0; k0 < KIP; k0 += 32) {
#pragma unroll
    for (int i = 0; i < O*8/256; ++i) {
      const int idx = tid + i*256;
      const int o = idx >> 3, kq = idx & 7;
      float4 a0 = make_float4(0.f, 0.f, 0.f, 0.f);
      float4 a1 = make_float4(0.f, 0.f, 0.f, 0.f);
      merge_p2<KIP>(PF, PH, el0, el1, o, (k0 >> 2) + kq, isbf, a0, a1);
      *(float4*)&wm[0][o][kq*4] = a0;
      *(float4*)&wm[1][o][kq*4] = a1;
    }
    __syncthreads();
#pragma unroll
    for (int kq = 0; kq < 8; ++kq) {
      const float4 xv0 = *(const float4*)&xg[0][b][k0 + kq*4];
      const float4 xv1 = *(const float4*)&xg[1][b][k0 + kq*4];
#pragma unroll
      for (int j = 0; j < 4; ++j) {
        const float4 w0 = *(const float4*)&wm[0][q + 16*j][kq*4];
        const float4 w1 = *(const float4*)&wm[1][q + 16*j][kq*4];
        ac0[j] += xv0.x*w0.x + xv0.y*w0.y + xv0.z*w0.z + xv0.w*w0.w;
        ac1[j] += xv1.x*w1.x + xv1.y*w1.y + xv1.z*w1.z + xv1.w*w1.w;
      }
    }
    __syncthreads();
  }
#pragma unroll
  for (int j = 0; j < 4; ++j) {
    const int o = q + 16*j;
    {
      const float hc = tanhf(ac0[j] + buv[n0*64 + o]);
      const float rr = g_rbuf[(size_t)n0*BH + b*64 + o];
      const float hold = hstate[(size_t)n0*BH + b*64 + o];
      hstate[(size_t)n0*BH + b*64 + o] = rr*hold + (1.f - rr)*hc;
    }
    {
      const float hc = tanhf(ac1[j] + buv[n1*64 + o]);
      const float rr = g_rbuf[(size_t)n1*BH + b*64 + o];
      const float hold = hstate[(size_t)n1*BH + b*64 + o];
      hstate[(size_t)n1*BH + b*64 + o] = rr*hold + (1.f - rr)*hc;
    }
  }
}

// sel: 0 = zero g_h[0..2SL), 1 = zero g_Sh[0..2SL)
__global__ void k_zero_f(int sel) {
  float* p = (sel == 0) ? g_h : g_Sh;
  const int i = blockIdx.x*256 + threadIdx.x;
  if (i < 2*SL_) p[i] = 0.f;
}

// out[b][hor][n] = sum_c h2[n][b*64+c]*cwf[hor][c] + cbf[hor]
__global__ __launch_bounds__(256) void k_conv(void* __restrict__ out) {
  const float* h2 = g_h + SL_;
  const int n = blockIdx.x, tid = threadIdx.x;
  __shared__ float hs[BH];
  for (int i = tid; i < BH; i += 256) hs[i] = h2[(size_t)n*BH + i];
  __syncthreads();
  const int isbf = g_flag[0];
  for (int i = tid; i < B_*HOR_; i += 256) {
    const int b = i / HOR_, hor = i - b*HOR_;
    float acc = g_cbf[hor];
#pragma unroll
    for (int c = 0; c < HID_; ++c) acc += hs[b*HID_ + c]*g_cwf[hor*HID_ + c];
    const size_t oi = (size_t)(b*HOR_ + hor)*N_ + n;
    if (isbf) ((bf16*)out)[oi] = f2b(acc);
    else      ((float*)out)[oi] = acc;
  }
}

// ---------------------------------------------------------------------------
extern "C" void kernel_launch(void* const* d_in, const int* in_sizes, int n_in,
                              void* d_out, int out_size, void* d_ws, size_t ws_size,
                              hipStream_t stream) {
  (void)out_size; (void)d_ws; (void)ws_size;

  // --- R30: identify inputs by element count (robust to reordering). ---
  static const long long cnt[12] = {
    393216,  // source 16*12*2048*1
    20480,   // node_embeddings 2048*10
    166400,  // Wg0 10*2*65*128
    1280,    // bg0 10*128
    83200,   // Wu0 10*2*65*64
    640,     // bu0 10*64
    327680,  // Wg1 10*2*128*128
    1280,    // bg1
    163840,  // Wu1 10*2*128*64
    640,     // bu1
    768,     // conv_w 12*64
    12       // conv_b
  };
  const void* in[12];
  bool ok = (n_in == 12) && (in_sizes != nullptr) && (d_in != nullptr);
  if (ok) {
    long long mx = 0;
    for (int i = 0; i < 12; ++i) if ((long long)in_sizes[i] > mx) mx = in_sizes[i];
    long long scale = mx / 393216LL;
    if (scale != 1 && scale != 2 && scale != 4) ok = false;
    if (ok && scale*393216LL != mx) ok = false;
    bool used[12] = {false,false,false,false,false,false,false,false,false,false,false,false};
    for (int k = 0; k < 12 && ok; ++k) {
      int found = -1;
      for (int i = 0; i < 12; ++i)
        if (!used[i] && (long long)in_sizes[i] == cnt[k]*scale) { found = i; break; }
      if (found < 0) ok = false;
      else { used[found] = true; in[k] = d_in[found]; }
    }
  }
  if (!ok) for (int k = 0; k < 12; ++k) in[k] = d_in[k];

  const void* src = in[0];
  const void* E   = in[1];
  const void* Wg0 = in[2];
  const void* bg0 = in[3];
  const void* Wu0 = in[4];
  const void* bu0 = in[5];
  const void* Wg1 = in[6];
  const void* bg1 = in[7];
  const void* Wu1 = in[8];
  const void* bu1 = in[9];
  const void* cw  = in[10];
  const void* cb  = in[11];

  auto cdiv = [](int a, int b) { return (a + b - 1) / b; };

  k_detect<<<dim3(1), 256, 0, stream>>>(E);

  // --- casts + setup ---
  k_castE  <<<dim3(cdiv(N_*ED_, 256)), 256, 0, stream>>>(E);
  k_castsrc<<<dim3(cdiv(BT*N_, 256)),  256, 0, stream>>>(src);
  k_castc  <<<dim3(cdiv(HOR_*HID_, 256)), 256, 0, stream>>>(cw, cb);
  k_prepP<0><<<dim3(cdiv(ED_*128*160, 256)), 256, 0, stream>>>(Wg0, 65, 160, 128, 0);
  k_prepP<0><<<dim3(cdiv(ED_*64*160,  256)), 256, 0, stream>>>(Wu0, 65, 160, 64, 1);
  k_prepP<1><<<dim3(cdiv(ED_*128*256, 256)), 256, 0, stream>>>(Wg1, 128, 256, 128, 2);
  k_prepP<1><<<dim3(cdiv(ED_*64*256,  256)), 256, 0, stream>>>(Wu1, 128, 256, 64, 3);
  k_matb<<<dim3(N_), 128, 0, stream>>>(bg0, 128, 0);
  k_matb<<<dim3(N_), 128, 0, stream>>>(bu0, 64,  1);
  k_matb<<<dim3(N_), 128, 0, stream>>>(bg1, 128, 2);
  k_matb<<<dim3(N_), 128, 0, stream>>>(bu1, 64,  3);
  k_softmax_S<<<dim3(N_), 256, 0, stream>>>();
  k_splitSrc<<<dim3(cdiv(BT*N_, 256)), 256, 0, stream>>>();

  // Sx0[n, bt] = sum_m S[n,m]*srcf[bt*N + m]  (split-bf16 MFMA gemm)
  k_gemmM<<<dim3(N_/128, BT/64), 256, 0, stream>>>(2, 2, BT, 2, 2, BT, 1 << 30);

  // zero recurrent states (h0|h2) + Sh_a|Sh_b
  k_zero_f<<<dim3((2*SL_ + 255)/256), 256, 0, stream>>>(0);
  k_zero_f<<<dim3((2*SL_ + 255)/256), 256, 0, stream>>>(1);

  // --- t = 0 (states zero: all Sh terms vanish except S@h1[0]) ---
  k_gateW2<0,160><<<dim3(N_/2), 256, 0, stream>>>(0);
  k_candW2f<0,160><<<dim3(N_/2), 256, 0, stream>>>(0);
  k_trsp<<<dim3(N_/64, BH/64), 256, 0, stream>>>(0, 0);           // h0 -> tmpT
  k_gemmM<<<dim3(N_/128, BH/64), 256, 0, stream>>>(0, 0, BH, 0, 0, BH, 1 << 30); // Sh_a = S@h1[0]
  k_gateW2<1,256><<<dim3(N_/2), 256, 0, stream>>>(0);
  k_candW2f<1,256><<<dim3(N_/2), 256, 0, stream>>>(0);
  k_trsp<<<dim3(N_/64, BH/64), 256, 0, stream>>>(1, 1);           // h2 -> h2T

  // --- t >= 1 ---
  for (int t = 1; t < T_; ++t) {
    k_gateW2<0,160><<<dim3(N_/2), 256, 0, stream>>>(t);
    k_trsp<<<dim3(N_/64, BH/64), 256, 0, stream>>>(2, 0);         // zh -> tmpT
    k_gemmM<<<dim3(N_/128, BH/64), 256, 0, stream>>>(0, 1, BH, 0, 1, BH, 1 << 30); // Sh_b = S@zh0
    k_candW2f<0,160><<<dim3(N_/2), 256, 0, stream>>>(t);
    k_trsp<<<dim3(N_/64, BH/64), 256, 0, stream>>>(0, 0);         // h0 -> tmpT
    // dual: Sh_a = S@h1t, Sh_b = S@h2
    k_gemmM<<<dim3(N_/128, 2*BH/64), 256, 0, stream>>>(0, 0, BH, 1, 1, BH, BH);
    k_gateW2<1,256><<<dim3(N_/2), 256, 0, stream>>>(t);
    k_trsp<<<dim3(N_/64, BH/64), 256, 0, stream>>>(2, 0);         // zh -> tmpT
    k_gemmM<<<dim3(N_/128, BH/64), 256, 0, stream>>>(0, 1, BH, 0, 1, BH, 1 << 30); // Sh_b = S@zh1
    k_candW2f<1,256><<<dim3(N_/2), 256, 0, stream>>>(t);
    k_trsp<<<dim3(N_/64, BH/64), 256, 0, stream>>>(1, 1);         // h2 -> h2T
  }

  // --- final conv ---
  k_conv<<<dim3(N_), 256, 0, stream>>>(d_out);
}

// Round 17
// 6272.904 us; speedup vs baseline: 1.0687x; 1.0687x over previous
//
#include <hip/hip_runtime.h>
#include <hip/hip_bf16.h>

// FP32-intermediate pipeline; R14 split-bf16 MFMA GEMM; R18 dual-n
// fallbacks; R19 gemmM 128x64/BK=64; R24 no scatter writes + k_trsp.
// R25-R29: five env-caused zero-output failures (ws_size/API contract
// changed; proven by R27's byte-identical failure of passing source).
// R30: module-scope statics + zero host API calls in kernel_launch +
// in_sizes-based input matching -> PASSED 6704us.
// R31: re-activate the premerge lever (R15/R16-validated; was throttled by
// the dead ws constraint) for ALL FOUR roles via +654MB statics. k_merge
// output == merge_p values exactly (fp32 round-trip) -> bitwise-same
// results. k_merge<160>+candWpm<0,160> run-proven (R24); other
// instantiations are the same templates, pointers mapped as in the
// R30-verified fallbacks.

#define B_    16
#define T_    12
#define N_    2048
#define HID_  64
#define ED_   10
#define HOR_  12
#define BH    (B_*HID_)    // 1024
#define BT    (B_*T_)      // 192
#define SL_   (N_*BH)      // 2097152

typedef __hip_bfloat16 bf16;
typedef __attribute__((ext_vector_type(8))) short short8;
typedef __attribute__((ext_vector_type(4))) float floatx4;

// ---------------------------------------------------------------------------
// Module-scope static buffers. ~97MB base + 654MB premerged tiers.
// ---------------------------------------------------------------------------
__device__ int            g_flag[64];
__device__ float          g_Ein[N_*ED_];
__device__ float          g_cwf[HOR_*HID_];
__device__ float          g_cbf[HOR_ + 4];
__device__ unsigned short g_Shi[N_*N_];
__device__ unsigned short g_Slo[N_*N_];
__device__ float          g_Wg0F[ED_*128*160];
__device__ float          g_Wu0F[ED_*64*160];
__device__ float          g_Wg1F[ED_*128*256];
__device__ float          g_Wu1F[ED_*64*256];
__device__ unsigned short g_Wg0H[ED_*128*160];
__device__ unsigned short g_Wu0H[ED_*64*160];
__device__ unsigned short g_Wg1H[ED_*128*256];
__device__ unsigned short g_Wu1H[ED_*64*256];
__device__ float          g_bgv0[N_*128];
__device__ float          g_buv0[N_*64];
__device__ float          g_bgv1[N_*128];
__device__ float          g_buv1[N_*64];
__device__ float          g_srcf[BT*N_];
__device__ unsigned short g_srcHi[BT*N_];
__device__ unsigned short g_srcLo[BT*N_];
__device__ float          g_Sx0[N_*BT];
__device__ float          g_h[2*SL_];        // h0 | h2
__device__ float          g_Sh[2*SL_];       // Sh_a | Sh_b
__device__ float          g_zh[SL_];
__device__ float          g_rbuf[SL_];
__device__ unsigned short g_tmpTh[SL_];
__device__ unsigned short g_tmpTl[SL_];
__device__ unsigned short g_h2Th[SL_];
__device__ unsigned short g_h2Tl[SL_];
// R31: premerged E-weighted weights WM[n][o][k] (fp32)
__device__ float          g_Wg0M[(size_t)N_*128*160];   // 168MB
__device__ float          g_Wu0M[(size_t)N_*64*160];    //  84MB
__device__ float          g_Wg1M[(size_t)N_*128*256];   // 268MB
__device__ float          g_Wu1M[(size_t)N_*64*256];    // 134MB

__device__ __forceinline__ float b2f(bf16 x){ return __bfloat162float(x); }
__device__ __forceinline__ bf16  f2b(float x){ return __float2bfloat16(x); }
__device__ __forceinline__ float bits2f(unsigned u) {
  union { float f; unsigned i; } c; c.i = u << 16; return c.f;
}
__device__ __forceinline__ float ldin(const void* p, size_t i, int isbf) {
  return isbf ? b2f(((const bf16*)p)[i]) : ((const float*)p)[i];
}
__device__ __forceinline__ void fma4(float4& a, float s, const float4& b) {
  a.x += s*b.x; a.y += s*b.y; a.z += s*b.z; a.w += s*b.w;
}

// ---------------------------------------------------------------------------
// dtype detector on E
// ---------------------------------------------------------------------------
__global__ void k_detect(const void* __restrict__ E) {
  __shared__ int cnt;
  if (threadIdx.x == 0) cnt = 0;
  __syncthreads();
  const unsigned* w = (const unsigned*)E;
  int c = 0;
  for (int i = threadIdx.x; i < 4096; i += 256) {
    const unsigned e = (w[i] >> 7) & 0xFFu;
    if (e >= 0x6Eu && e <= 0x86u) ++c;
  }
  atomicAdd(&cnt, c);
  __syncthreads();
  if (threadIdx.x == 0) g_flag[0] = (cnt > 2048) ? 1 : 0;
}

// --- input casts to fp32 internal buffers ---
__global__ void k_castE(const void* __restrict__ E) {
  const int i = blockIdx.x*256 + threadIdx.x;
  if (i < N_*ED_) g_Ein[i] = ldin(E, i, g_flag[0]);
}
__global__ void k_castsrc(const void* __restrict__ src) {
  const int i = blockIdx.x*256 + threadIdx.x;
  if (i < B_*T_*N_) g_srcf[i] = ldin(src, i, g_flag[0]);
}
__global__ void k_castc(const void* __restrict__ cw, const void* __restrict__ cb) {
  const int i = blockIdx.x*256 + threadIdx.x;
  const int f = g_flag[0];
  if (i < HOR_*HID_) g_cwf[i] = ldin(cw, i, f);
  if (i < HOR_)      g_cbf[i] = ldin(cb, i, f);
}

// ---------------------------------------------------------------------------
// S = softmax(relu(Ein @ Ein^T), axis=1) -> hi/lo bf16 pair directly.
// ---------------------------------------------------------------------------
__global__ __launch_bounds__(256) void k_softmax_S() {
  bf16* Sh = (bf16*)g_Shi;
  bf16* Sl = (bf16*)g_Slo;
  const int n = blockIdx.x, tid = threadIdx.x;
  __shared__ float er[ED_];
  __shared__ float red[4];
  if (tid < ED_) er[tid] = g_Ein[n*ED_ + tid];
  __syncthreads();
  float e[ED_];
#pragma unroll
  for (int d = 0; d < ED_; ++d) e[d] = er[d];
  float v[8];
  float mx = 0.f;
#pragma unroll
  for (int j = 0; j < 8; ++j) {
    const int m = tid + j*256;
    float dot = 0.f;
#pragma unroll
    for (int d = 0; d < ED_; ++d) dot += e[d]*g_Ein[m*ED_ + d];
    v[j] = fmaxf(dot, 0.f);
    mx = fmaxf(mx, v[j]);
  }
  for (int o = 32; o; o >>= 1) mx = fmaxf(mx, __shfl_xor(mx, o, 64));
  if ((tid & 63) == 0) red[tid >> 6] = mx;
  __syncthreads();
  mx = fmaxf(fmaxf(red[0], red[1]), fmaxf(red[2], red[3]));
  __syncthreads();
  float sum = 0.f;
#pragma unroll
  for (int j = 0; j < 8; ++j) { v[j] = __expf(v[j] - mx); sum += v[j]; }
  for (int o = 32; o; o >>= 1) sum += __shfl_xor(sum, o, 64);
  if ((tid & 63) == 0) red[tid >> 6] = sum;
  __syncthreads();
  sum = red[0] + red[1] + red[2] + red[3];
  const float inv = 1.f / sum;
#pragma unroll
  for (int j = 0; j < 8; ++j) {
    const float sv = v[j]*inv;
    const size_t idx = (size_t)n*N_ + tid + j*256;
    const bf16 h = f2b(sv);
    Sh[idx] = h;
    Sl[idx] = f2b(sv - b2f(h));
  }
}

// split srcf -> hi/lo bf16 pair
__global__ void k_splitSrc() {
  const int i = blockIdx.x*256 + threadIdx.x;
  if (i < BT*N_) {
    const float v = g_srcf[i];
    const bf16 h = f2b(v);
    ((bf16*)g_srcHi)[i] = h;
    ((bf16*)g_srcLo)[i] = f2b(v - b2f(h));
  }
}

// ---------------------------------------------------------------------------
// Tiled transpose+split: X[n][BH] fp32 -> Th[c][N_], Tl[c][N_] bf16.
// xsel: 0=h0, 1=h2, 2=zh. dsel: 0=tmpT, 1=h2T.
// ---------------------------------------------------------------------------
__global__ __launch_bounds__(256) void k_trsp(int xsel, int dsel) {
  const float* X = (xsel == 0) ? g_h : (xsel == 1) ? (g_h + SL_) : g_zh;
  bf16* Th = (bf16*)((dsel == 0) ? g_tmpTh : g_h2Th);
  bf16* Tl = (bf16*)((dsel == 0) ? g_tmpTl : g_h2Tl);
  const int n0 = blockIdx.x * 64;
  const int c0 = blockIdx.y * 64;
  __shared__ float t[64][68];
  const int tid = threadIdx.x;
  {
    const int r = tid >> 2, q4 = (tid & 3) * 16;
    const float4* src = (const float4*)(X + (size_t)(n0 + r)*BH + c0 + q4);
#pragma unroll
    for (int u = 0; u < 4; ++u)
      *(float4*)&t[r][q4 + u*4] = src[u];
  }
  __syncthreads();
  {
    const int c = tid >> 2, sg = (tid & 3) * 16;
    bf16 hb[16], lb[16];
#pragma unroll
    for (int i = 0; i < 16; ++i) {
      const float v = t[sg + i][c];
      const bf16 h = f2b(v);
      hb[i] = h;
      lb[i] = f2b(v - b2f(h));
    }
    bf16* dh = Th + (size_t)(c0 + c)*N_ + n0 + sg;
    bf16* dl = Tl + (size_t)(c0 + c)*N_ + n0 + sg;
    *(uint4*)dh       = *(uint4*)&hb[0];
    *(uint4*)(dh + 8) = *(uint4*)&hb[8];
    *(uint4*)dl       = *(uint4*)&lb[0];
    *(uint4*)(dl + 8) = *(uint4*)&lb[8];
  }
}

// ---------------------------------------------------------------------------
// Basis weights -> PACKED d-interleaved layout, fp32 + bf16.
// wsel: 0=Wg0, 1=Wu0, 2=Wg1, 3=Wu1.
// ---------------------------------------------------------------------------
template<int LAYER>
__global__ __launch_bounds__(256) void k_prepP(const void* __restrict__ Wb,
                                               int KIin, int KIP, int O,
                                               int wsel) {
  float* PF = (wsel == 0) ? g_Wg0F : (wsel == 1) ? g_Wu0F
            : (wsel == 2) ? g_Wg1F : g_Wu1F;
  bf16* PH = (bf16*)((wsel == 0) ? g_Wg0H : (wsel == 1) ? g_Wu0H
            : (wsel == 2) ? g_Wg1H : g_Wu1H);
  const int idx = blockIdx.x*256 + threadIdx.x;
  if (idx >= ED_*O*KIP) return;
  const int d = idx / (O*KIP), rem = idx - d*O*KIP;
  const int o = rem / KIP, kp = rem - o*KIP;
  int cheb, i; bool valid;
  if (LAYER == 0) {
    cheb = (kp >= 80) ? 1 : 0;
    const int local = kp - cheb*80;
    if (local < 64)       { i = local + 1; valid = true; }
    else if (local == 64) { i = 0;         valid = true; }
    else                  { i = 0;         valid = false; }
  } else {
    cheb = kp >> 7; i = kp & 127; valid = true;
  }
  float v = 0.f;
  if (valid) v = ldin(Wb, (size_t)((d*2 + cheb)*KIin + i)*O + o, g_flag[0]);
  const int kg = kp >> 2, e = kp & 3;
  const size_t pi = ((size_t)(o*(KIP/4) + kg)*ED_ + d)*4 + e;
  PF[pi] = v;
  PH[pi] = f2b(v);
}

// bias vectors: outv[n][o] = sum_d Ein[n,d]*bb[d][o]
__global__ __launch_bounds__(128) void k_matb(const void* __restrict__ bb,
                                              int O, int osel) {
  float* outv = (osel == 0) ? g_bgv0 : (osel == 1) ? g_buv0
              : (osel == 2) ? g_bgv1 : g_buv1;
  const int n = blockIdx.x, tid = threadIdx.x;
  if (tid >= O) return;
  const int f = g_flag[0];
  float acc = 0.f;
#pragma unroll
  for (int d = 0; d < ED_; ++d) acc += g_Ein[n*ED_ + d]*ldin(bb, d*O + tid, f);
  outv[n*O + tid] = acc;
}

// Packed merge (single-n; R13 arithmetic)
template<int KIP>
__device__ __forceinline__ float4 merge_p(const float* __restrict__ PF,
                                          const bf16* __restrict__ PH,
                                          const float* el, int o, int kg,
                                          int isbf) {
  float4 a4 = make_float4(0.f, 0.f, 0.f, 0.f);
  const size_t gbase = (size_t)(o*(KIP/4) + kg)*(ED_*4);
  if (isbf) {
    const uint4* g = (const uint4*)(PH + gbase);
#pragma unroll
    for (int i = 0; i < 5; ++i) {
      const uint4 w = g[i];
      const float e0 = el[2*i], e1 = el[2*i + 1];
      a4.x += e0*bits2f(w.x & 0xFFFFu); a4.y += e0*bits2f(w.x >> 16);
      a4.z += e0*bits2f(w.y & 0xFFFFu); a4.w += e0*bits2f(w.y >> 16);
      a4.x += e1*bits2f(w.z & 0xFFFFu); a4.y += e1*bits2f(w.z >> 16);
      a4.z += e1*bits2f(w.w & 0xFFFFu); a4.w += e1*bits2f(w.w >> 16);
    }
  } else {
    const float4* g = (const float4*)(PF + gbase);
#pragma unroll
    for (int d = 0; d < ED_; ++d)
      fma4(a4, el[d], g[d]);
  }
  return a4;
}

// ---------------------------------------------------------------------------
// R31: one-time merged-weight build. WM[n][o][k] (k contiguous), fp32.
// wsel: 0=Wg0M, 1=Wu0M, 2=Wg1M, 3=Wu1M.
// ---------------------------------------------------------------------------
template<int KIP>
__global__ __launch_bounds__(256) void k_merge(int O, int wsel) {
  const float* PF = (wsel == 0) ? g_Wg0F : (wsel == 1) ? g_Wu0F
                  : (wsel == 2) ? g_Wg1F : g_Wu1F;
  const bf16* PH = (const bf16*)((wsel == 0) ? g_Wg0H : (wsel == 1) ? g_Wu0H
                  : (wsel == 2) ? g_Wg1H : g_Wu1H);
  float* WM = (wsel == 0) ? g_Wg0M : (wsel == 1) ? g_Wu0M
            : (wsel == 2) ? g_Wg1M : g_Wu1M;
  const int n = blockIdx.x;
  const int idx = blockIdx.y*256 + threadIdx.x;
  __shared__ float es[ED_];
  if (threadIdx.x < ED_) es[threadIdx.x] = g_Ein[n*ED_ + threadIdx.x];
  __syncthreads();
  if (idx >= O*(KIP/4)) return;
  const int o = idx / (KIP/4), kg = idx - o*(KIP/4);
  float el[ED_];
#pragma unroll
  for (int d = 0; d < ED_; ++d) el[d] = es[d];
  const float4 a4 = merge_p<KIP>(PF, PH, el, o, kg, g_flag[0]);
  *(float4*)&WM[((size_t)n*O + o)*KIP + kg*4] = a4;
}

// ---------------------------------------------------------------------------
// Split-bf16 MFMA GEMM (R19): C(n,c) = sum_m S[n,m]*X[m,c]. 128x64 tile.
// xsel: 0=tmpT, 1=h2T, 2=srcT. csel: 0=Sh_a, 1=Sh_b, 2=Sx0.
// ---------------------------------------------------------------------------
__global__ __launch_bounds__(256) void k_gemmM(int x1, int c1, int ldc1,
                                               int x2, int c2, int ldc2,
                                               int split) {
  const bf16* Sh = (const bf16*)g_Shi;
  const bf16* Sl = (const bf16*)g_Slo;
  const int bm = blockIdx.x * 128;
  int bc = blockIdx.y * 64;
  int xs = x1, cs = c1, ldc = ldc1;
  if (bc >= split) { xs = x2; cs = c2; ldc = ldc2; bc -= split; }
  const bf16* Xh = (const bf16*)((xs == 0) ? g_tmpTh : (xs == 1) ? g_h2Th : g_srcHi);
  const bf16* Xl = (const bf16*)((xs == 0) ? g_tmpTl : (xs == 1) ? g_h2Tl : g_srcLo);
  float* C = (cs == 0) ? g_Sh : (cs == 1) ? (g_Sh + SL_) : g_Sx0;

  __shared__ __align__(16) bf16 Ah[128][72];
  __shared__ __align__(16) bf16 Al[128][72];
  __shared__ __align__(16) bf16 Bh[64][72];
  __shared__ __align__(16) bf16 Bl[64][72];
  const int tid = threadIdx.x;
  const int wave = tid >> 6, lane = tid & 63, q = lane >> 4, ln = lane & 15;
  const int wm = wave >> 1, wn = wave & 1;
  const int srow = tid >> 3, scol = (tid & 7) * 8;

  floatx4 acc[4][2];
#pragma unroll
  for (int mt = 0; mt < 4; ++mt)
#pragma unroll
    for (int nt = 0; nt < 2; ++nt) acc[mt][nt] = (floatx4){0.f,0.f,0.f,0.f};

  for (int mk = 0; mk < N_; mk += 64) {
#pragma unroll
    for (int i = 0; i < 4; ++i) {
      const int r = i*32 + srow;
      *(uint4*)&Ah[r][scol] = *(const uint4*)(Sh + (size_t)(bm + r)*N_ + mk + scol);
      *(uint4*)&Al[r][scol] = *(const uint4*)(Sl + (size_t)(bm + r)*N_ + mk + scol);
    }
#pragma unroll
    for (int i = 0; i < 2; ++i) {
      const int r = i*32 + srow;
      *(uint4*)&Bh[r][scol] = *(const uint4*)(Xh + (size_t)(bc + r)*N_ + mk + scol);
      *(uint4*)&Bl[r][scol] = *(const uint4*)(Xl + (size_t)(bc + r)*N_ + mk + scol);
    }
    __syncthreads();
#pragma unroll
    for (int ks = 0; ks < 64; ks += 32) {
      short8 ah[4], al[4], bh[2], bl[2];
#pragma unroll
      for (int mt = 0; mt < 4; ++mt) {
        ah[mt] = *(const short8*)&Ah[wm*64 + mt*16 + ln][ks + q*8];
        al[mt] = *(const short8*)&Al[wm*64 + mt*16 + ln][ks + q*8];
      }
#pragma unroll
      for (int nt = 0; nt < 2; ++nt) {
        bh[nt] = *(const short8*)&Bh[wn*32 + nt*16 + ln][ks + q*8];
        bl[nt] = *(const short8*)&Bl[wn*32 + nt*16 + ln][ks + q*8];
      }
#pragma unroll
      for (int mt = 0; mt < 4; ++mt)
#pragma unroll
        for (int nt = 0; nt < 2; ++nt) {
          acc[mt][nt] = __builtin_amdgcn_mfma_f32_16x16x32_bf16(ah[mt], bh[nt], acc[mt][nt], 0, 0, 0);
          acc[mt][nt] = __builtin_amdgcn_mfma_f32_16x16x32_bf16(al[mt], bh[nt], acc[mt][nt], 0, 0, 0);
          acc[mt][nt] = __builtin_amdgcn_mfma_f32_16x16x32_bf16(ah[mt], bl[nt], acc[mt][nt], 0, 0, 0);
        }
    }
    __syncthreads();
  }
#pragma unroll
  for (int mt = 0; mt < 4; ++mt)
#pragma unroll
    for (int nt = 0; nt < 2; ++nt)
#pragma unroll
      for (int r = 0; r < 4; ++r)
        C[(size_t)(bm + wm*64 + mt*16 + q*4 + r)*ldc + bc + wn*32 + nt*16 + ln] =
            acc[mt][nt][r];
}

// ---------------------------------------------------------------------------
// xg builder (float4): xg[b][k], padded row stride KIPP (R13 verbatim).
// ---------------------------------------------------------------------------
template<int LAYER, int KIP, int KIPP>
__device__ __forceinline__ void build4(float (*xg)[KIPP],
                                       const float* p0, const float* p1,
                                       const float* p2, const float* p3,
                                       int n, int t, int tid) {
  constexpr int NQ = KIP/4;
  for (int idx = tid; idx < B_*NQ; idx += 256) {
    const int b = idx / NQ, k = (idx - b*NQ) * 4;
    float4 v = make_float4(0.f, 0.f, 0.f, 0.f);
    if (LAYER == 1) {
      const float* rg = (k < 64) ? p0 : (k < 128) ? p1 : (k < 192) ? p2 : p3;
      v = *(const float4*)(rg + (size_t)n*BH + b*64 + (k & 63));
    } else {
      if (k < 64)        v = *(const float4*)(p0 + (size_t)n*BH + b*64 + k);
      else if (k == 64)  v.x = p1[(size_t)(b*T_ + t)*N_ + n];
      else if (k >= 80 && k < 144)
                         v = *(const float4*)(p2 + (size_t)n*BH + b*64 + (k - 80));
      else if (k == 144) v.x = p3[(size_t)n*BT + b*T_ + t];
    }
    *(float4*)&xg[b][k] = v;
  }
}

// ---------------------------------------------------------------------------
// R31: Gate premerged — stream WM[n] tiles (stage->sync->compute->sync).
// Pointer mapping identical to the R30-verified k_gateW2.
// ---------------------------------------------------------------------------
template<int LAYER, int KIP>
__global__ __launch_bounds__(256, 2) void k_gateWpm(int t) {
  constexpr int KIPP = KIP + 4;
  constexpr int O = 128;
  const float* WM = (LAYER == 0) ? g_Wg0M : g_Wg1M;
  const float* bgv = (LAYER == 0) ? g_bgv0 : g_bgv1;
  const float* p0 = g_h;
  const float* p1 = (LAYER == 0) ? g_srcf : (g_h + SL_);
  const float* p2 = g_Sh;
  const float* p3 = (LAYER == 0) ? g_Sx0 : (g_Sh + SL_);
  const float* hstate = (LAYER == 0) ? g_h : (g_h + SL_);
  const int n = blockIdx.x, tid = threadIdx.x;
  __shared__ float xg[B_][KIPP];
  __shared__ float wm[O][36];
  build4<LAYER, KIP, KIPP>(xg, p0, p1, p2, p3, n, t, tid);

  const float* WMn = WM + (size_t)n*O*KIP;
  const int b = tid >> 4, q = tid & 15;
  float acc[8];
#pragma unroll
  for (int j = 0; j < 8; ++j) acc[j] = 0.f;

  for (int k0 = 0; k0 < KIP; k0 += 32) {
#pragma unroll
    for (int i = 0; i < O*8/256; ++i) {
      const int idx = tid + i*256;
      const int o = idx >> 3, kq = idx & 7;
      *(float4*)&wm[o][kq*4] =
          *(const float4*)(WMn + (size_t)o*KIP + k0 + kq*4);
    }
    __syncthreads();   // wm ready (and xg on first iter)
#pragma unroll
    for (int kq = 0; kq < 8; ++kq) {
      const float4 xv = *(const float4*)&xg[b][k0 + kq*4];
#pragma unroll
      for (int j = 0; j < 8; ++j) {
        const float4 wv = *(const float4*)&wm[q + 16*j][kq*4];
        acc[j] += xv.x*wv.x + xv.y*wv.y + xv.z*wv.z + xv.w*wv.w;
      }
    }
    __syncthreads();
  }
#pragma unroll
  for (int j = 0; j < 8; ++j) {
    const int o = q + 16*j;
    float s = acc[j] + bgv[n*128 + o];
    s = 1.f/(1.f + __expf(-s));
    if (o < HID_) {
      g_zh[(size_t)n*BH + b*64 + o] = s*hstate[(size_t)n*BH + b*64 + o];
    } else {
      g_rbuf[(size_t)n*BH + b*64 + (o - HID_)] = s;
    }
  }
}

// ---------------------------------------------------------------------------
// R31: Candidate premerged — same stream structure (O=64).
// Pointer mapping identical to the R30-verified k_candW2f.
// ---------------------------------------------------------------------------
template<int LAYER, int KIP>
__global__ __launch_bounds__(256, 2) void k_candWpm(int t) {
  constexpr int KIPP = KIP + 4;
  constexpr int O = 64;
  const float* WM = (LAYER == 0) ? g_Wu0M : g_Wu1M;
  const float* buv = (LAYER == 0) ? g_buv0 : g_buv1;
  const float* p0 = (LAYER == 0) ? g_zh : g_h;
  const float* p1 = (LAYER == 0) ? g_srcf : g_zh;
  const float* p2 = (LAYER == 0) ? (g_Sh + SL_) : g_Sh;
  const float* p3 = (LAYER == 0) ? g_Sx0 : (g_Sh + SL_);
  float* hstate = (LAYER == 0) ? g_h : (g_h + SL_);
  const int n = blockIdx.x, tid = threadIdx.x;
  __shared__ float xg[B_][KIPP];
  __shared__ float wm[O][36];
  build4<LAYER, KIP, KIPP>(xg, p0, p1, p2, p3, n, t, tid);

  const float* WMn = WM + (size_t)n*O*KIP;
  const int b = tid >> 4, q = tid & 15;
  float acc[4];
#pragma unroll
  for (int j = 0; j < 4; ++j) acc[j] = 0.f;

  for (int k0 = 0; k0 < KIP; k0 += 32) {
#pragma unroll
    for (int i = 0; i < O*8/256; ++i) {
      const int idx = tid + i*256;
      const int o = idx >> 3, kq = idx & 7;
      *(float4*)&wm[o][kq*4] =
          *(const float4*)(WMn + (size_t)o*KIP + k0 + kq*4);
    }
    __syncthreads();
#pragma unroll
    for (int kq = 0; kq < 8; ++kq) {
      const float4 xv = *(const float4*)&xg[b][k0 + kq*4];
#pragma unroll
      for (int j = 0; j < 4; ++j) {
        const float4 wv = *(const float4*)&wm[q + 16*j][kq*4];
        acc[j] += xv.x*wv.x + xv.y*wv.y + xv.z*wv.z + xv.w*wv.w;
      }
    }
    __syncthreads();
  }
#pragma unroll
  for (int j = 0; j < 4; ++j) {
    const int o = q + 16*j;
    const float hc = tanhf(acc[j] + buv[n*64 + o]);
    const float rr = g_rbuf[(size_t)n*BH + b*64 + o];
    const float hold = hstate[(size_t)n*BH + b*64 + o];
    hstate[(size_t)n*BH + b*64 + o] = rr*hold + (1.f - rr)*hc;
  }
}

// sel: 0 = zero g_h[0..2SL), 1 = zero g_Sh[0..2SL)
__global__ void k_zero_f(int sel) {
  float* p = (sel == 0) ? g_h : g_Sh;
  const int i = blockIdx.x*256 + threadIdx.x;
  if (i < 2*SL_) p[i] = 0.f;
}

// out[b][hor][n] = sum_c h2[n][b*64+c]*cwf[hor][c] + cbf[hor]
__global__ __launch_bounds__(256) void k_conv(void* __restrict__ out) {
  const float* h2 = g_h + SL_;
  const int n = blockIdx.x, tid = threadIdx.x;
  __shared__ float hs[BH];
  for (int i = tid; i < BH; i += 256) hs[i] = h2[(size_t)n*BH + i];
  __syncthreads();
  const int isbf = g_flag[0];
  for (int i = tid; i < B_*HOR_; i += 256) {
    const int b = i / HOR_, hor = i - b*HOR_;
    float acc = g_cbf[hor];
#pragma unroll
    for (int c = 0; c < HID_; ++c) acc += hs[b*HID_ + c]*g_cwf[hor*HID_ + c];
    const size_t oi = (size_t)(b*HOR_ + hor)*N_ + n;
    if (isbf) ((bf16*)out)[oi] = f2b(acc);
    else      ((float*)out)[oi] = acc;
  }
}

// ---------------------------------------------------------------------------
extern "C" void kernel_launch(void* const* d_in, const int* in_sizes, int n_in,
                              void* d_out, int out_size, void* d_ws, size_t ws_size,
                              hipStream_t stream) {
  (void)out_size; (void)d_ws; (void)ws_size;

  // --- identify inputs by element count (robust to reordering). ---
  static const long long cnt[12] = {
    393216, 20480, 166400, 1280, 83200, 640,
    327680, 1280, 163840, 640, 768, 12
  };
  const void* in[12];
  bool ok = (n_in == 12) && (in_sizes != nullptr) && (d_in != nullptr);
  if (ok) {
    long long mx = 0;
    for (int i = 0; i < 12; ++i) if ((long long)in_sizes[i] > mx) mx = in_sizes[i];
    long long scale = mx / 393216LL;
    if (scale != 1 && scale != 2 && scale != 4) ok = false;
    if (ok && scale*393216LL != mx) ok = false;
    bool used[12] = {false,false,false,false,false,false,false,false,false,false,false,false};
    for (int k = 0; k < 12 && ok; ++k) {
      int found = -1;
      for (int i = 0; i < 12; ++i)
        if (!used[i] && (long long)in_sizes[i] == cnt[k]*scale) { found = i; break; }
      if (found < 0) ok = false;
      else { used[found] = true; in[k] = d_in[found]; }
    }
  }
  if (!ok) for (int k = 0; k < 12; ++k) in[k] = d_in[k];

  const void* src = in[0];
  const void* E   = in[1];
  const void* Wg0 = in[2];
  const void* bg0 = in[3];
  const void* Wu0 = in[4];
  const void* bu0 = in[5];
  const void* Wg1 = in[6];
  const void* bg1 = in[7];
  const void* Wu1 = in[8];
  const void* bu1 = in[9];
  const void* cw  = in[10];
  const void* cb  = in[11];

  auto cdiv = [](int a, int b) { return (a + b - 1) / b; };

  k_detect<<<dim3(1), 256, 0, stream>>>(E);

  // --- casts + setup ---
  k_castE  <<<dim3(cdiv(N_*ED_, 256)), 256, 0, stream>>>(E);
  k_castsrc<<<dim3(cdiv(BT*N_, 256)),  256, 0, stream>>>(src);
  k_castc  <<<dim3(cdiv(HOR_*HID_, 256)), 256, 0, stream>>>(cw, cb);
  k_prepP<0><<<dim3(cdiv(ED_*128*160, 256)), 256, 0, stream>>>(Wg0, 65, 160, 128, 0);
  k_prepP<0><<<dim3(cdiv(ED_*64*160,  256)), 256, 0, stream>>>(Wu0, 65, 160, 64, 1);
  k_prepP<1><<<dim3(cdiv(ED_*128*256, 256)), 256, 0, stream>>>(Wg1, 128, 256, 128, 2);
  k_prepP<1><<<dim3(cdiv(ED_*64*256,  256)), 256, 0, stream>>>(Wu1, 128, 256, 64, 3);
  k_matb<<<dim3(N_), 128, 0, stream>>>(bg0, 128, 0);
  k_matb<<<dim3(N_), 128, 0, stream>>>(bu0, 64,  1);
  k_matb<<<dim3(N_), 128, 0, stream>>>(bg1, 128, 2);
  k_matb<<<dim3(N_), 128, 0, stream>>>(bu1, 64,  3);
  k_softmax_S<<<dim3(N_), 256, 0, stream>>>();
  k_splitSrc<<<dim3(cdiv(BT*N_, 256)), 256, 0, stream>>>();

  // --- one-time merged weights (all four tiers; R31) ---
  k_merge<160><<<dim3(N_, 20), 256, 0, stream>>>(128, 0);   // Wg0M
  k_merge<160><<<dim3(N_, 10), 256, 0, stream>>>(64,  1);   // Wu0M
  k_merge<256><<<dim3(N_, 32), 256, 0, stream>>>(128, 2);   // Wg1M
  k_merge<256><<<dim3(N_, 16), 256, 0, stream>>>(64,  3);   // Wu1M

  // Sx0[n, bt] = sum_m S[n,m]*srcf[bt*N + m]  (split-bf16 MFMA gemm)
  k_gemmM<<<dim3(N_/128, BT/64), 256, 0, stream>>>(2, 2, BT, 2, 2, BT, 1 << 30);

  // zero recurrent states (h0|h2) + Sh_a|Sh_b
  k_zero_f<<<dim3((2*SL_ + 255)/256), 256, 0, stream>>>(0);
  k_zero_f<<<dim3((2*SL_ + 255)/256), 256, 0, stream>>>(1);

  // --- t = 0 (states zero: all Sh terms vanish except S@h1[0]) ---
  k_gateWpm<0,160><<<dim3(N_), 256, 0, stream>>>(0);
  k_candWpm<0,160><<<dim3(N_), 256, 0, stream>>>(0);
  k_trsp<<<dim3(N_/64, BH/64), 256, 0, stream>>>(0, 0);           // h0 -> tmpT
  k_gemmM<<<dim3(N_/128, BH/64), 256, 0, stream>>>(0, 0, BH, 0, 0, BH, 1 << 30); // Sh_a = S@h1[0]
  k_gateWpm<1,256><<<dim3(N_), 256, 0, stream>>>(0);
  k_candWpm<1,256><<<dim3(N_), 256, 0, stream>>>(0);
  k_trsp<<<dim3(N_/64, BH/64), 256, 0, stream>>>(1, 1);           // h2 -> h2T

  // --- t >= 1 ---
  for (int t = 1; t < T_; ++t) {
    k_gateWpm<0,160><<<dim3(N_), 256, 0, stream>>>(t);
    k_trsp<<<dim3(N_/64, BH/64), 256, 0, stream>>>(2, 0);         // zh -> tmpT
    k_gemmM<<<dim3(N_/128, BH/64), 256, 0, stream>>>(0, 1, BH, 0, 1, BH, 1 << 30); // Sh_b = S@zh0
    k_candWpm<0,160><<<dim3(N_), 256, 0, stream>>>(t);
    k_trsp<<<dim3(N_/64, BH/64), 256, 0, stream>>>(0, 0);         // h0 -> tmpT
    // dual: Sh_a = S@h1t, Sh_b = S@h2
    k_gemmM<<<dim3(N_/128, 2*BH/64), 256, 0, stream>>>(0, 0, BH, 1, 1, BH, BH);
    k_gateWpm<1,256><<<dim3(N_), 256, 0, stream>>>(t);
    k_trsp<<<dim3(N_/64, BH/64), 256, 0, stream>>>(2, 0);         // zh -> tmpT
    k_gemmM<<<dim3(N_/128, BH/64), 256, 0, stream>>>(0, 1, BH, 0, 1, BH, 1 << 30); // Sh_b = S@zh1
    k_candWpm<1,256><<<dim3(N_), 256, 0, stream>>>(t);
    k_trsp<<<dim3(N_/64, BH/64), 256, 0, stream>>>(1, 1);         // h2 -> h2T
  }

  // --- final conv ---
  k_conv<<<dim3(N_), 256, 0, stream>>>(d_out);
}

// Round 18
// 6244.192 us; speedup vs baseline: 1.0737x; 1.0046x over previous
//
#include <hip/hip_runtime.h>
#include <hip/hip_bf16.h>

// FP32-intermediate pipeline; R14 split-bf16 MFMA GEMM; R19 gemmM
// 128x64/BK=64; R24 no scatter writes + k_trsp; R30 module statics +
// zero host API calls + in_sizes input matching (PASSED 6704us);
// R31 all-four premerged WM tiers as statics (PASSED 6273us; merges
// ~420us one-time, streams off the top-5).
// R32: raise stream-kernel occupancy. The premerged gate/cand kernels are
// PURE-READ streams (R24 removed all scatter writes), so the R20/R23
// "occupancy hurts" evidence (write-amp) no longer applies, and R25's
// launch-bounds trial was never really tested (env-caused failure, proven
// by R27). Change __launch_bounds__(256,2) -> (256,4) on k_gateWpm /
// k_candWpm only (LDS 35KB/26KB allows 4 blocks/CU; VGPR cap 128 is
// ample). No arithmetic change -> absmax identical.

#define B_    16
#define T_    12
#define N_    2048
#define HID_  64
#define ED_   10
#define HOR_  12
#define BH    (B_*HID_)    // 1024
#define BT    (B_*T_)      // 192
#define SL_   (N_*BH)      // 2097152

typedef __hip_bfloat16 bf16;
typedef __attribute__((ext_vector_type(8))) short short8;
typedef __attribute__((ext_vector_type(4))) float floatx4;

// ---------------------------------------------------------------------------
// Module-scope static buffers. ~97MB base + 654MB premerged tiers.
// ---------------------------------------------------------------------------
__device__ int            g_flag[64];
__device__ float          g_Ein[N_*ED_];
__device__ float          g_cwf[HOR_*HID_];
__device__ float          g_cbf[HOR_ + 4];
__device__ unsigned short g_Shi[N_*N_];
__device__ unsigned short g_Slo[N_*N_];
__device__ float          g_Wg0F[ED_*128*160];
__device__ float          g_Wu0F[ED_*64*160];
__device__ float          g_Wg1F[ED_*128*256];
__device__ float          g_Wu1F[ED_*64*256];
__device__ unsigned short g_Wg0H[ED_*128*160];
__device__ unsigned short g_Wu0H[ED_*64*160];
__device__ unsigned short g_Wg1H[ED_*128*256];
__device__ unsigned short g_Wu1H[ED_*64*256];
__device__ float          g_bgv0[N_*128];
__device__ float          g_buv0[N_*64];
__device__ float          g_bgv1[N_*128];
__device__ float          g_buv1[N_*64];
__device__ float          g_srcf[BT*N_];
__device__ unsigned short g_srcHi[BT*N_];
__device__ unsigned short g_srcLo[BT*N_];
__device__ float          g_Sx0[N_*BT];
__device__ float          g_h[2*SL_];        // h0 | h2
__device__ float          g_Sh[2*SL_];       // Sh_a | Sh_b
__device__ float          g_zh[SL_];
__device__ float          g_rbuf[SL_];
__device__ unsigned short g_tmpTh[SL_];
__device__ unsigned short g_tmpTl[SL_];
__device__ unsigned short g_h2Th[SL_];
__device__ unsigned short g_h2Tl[SL_];
// premerged E-weighted weights WM[n][o][k] (fp32)
__device__ float          g_Wg0M[(size_t)N_*128*160];   // 168MB
__device__ float          g_Wu0M[(size_t)N_*64*160];    //  84MB
__device__ float          g_Wg1M[(size_t)N_*128*256];   // 268MB
__device__ float          g_Wu1M[(size_t)N_*64*256];    // 134MB

__device__ __forceinline__ float b2f(bf16 x){ return __bfloat162float(x); }
__device__ __forceinline__ bf16  f2b(float x){ return __float2bfloat16(x); }
__device__ __forceinline__ float bits2f(unsigned u) {
  union { float f; unsigned i; } c; c.i = u << 16; return c.f;
}
__device__ __forceinline__ float ldin(const void* p, size_t i, int isbf) {
  return isbf ? b2f(((const bf16*)p)[i]) : ((const float*)p)[i];
}
__device__ __forceinline__ void fma4(float4& a, float s, const float4& b) {
  a.x += s*b.x; a.y += s*b.y; a.z += s*b.z; a.w += s*b.w;
}

// ---------------------------------------------------------------------------
// dtype detector on E
// ---------------------------------------------------------------------------
__global__ void k_detect(const void* __restrict__ E) {
  __shared__ int cnt;
  if (threadIdx.x == 0) cnt = 0;
  __syncthreads();
  const unsigned* w = (const unsigned*)E;
  int c = 0;
  for (int i = threadIdx.x; i < 4096; i += 256) {
    const unsigned e = (w[i] >> 7) & 0xFFu;
    if (e >= 0x6Eu && e <= 0x86u) ++c;
  }
  atomicAdd(&cnt, c);
  __syncthreads();
  if (threadIdx.x == 0) g_flag[0] = (cnt > 2048) ? 1 : 0;
}

// --- input casts to fp32 internal buffers ---
__global__ void k_castE(const void* __restrict__ E) {
  const int i = blockIdx.x*256 + threadIdx.x;
  if (i < N_*ED_) g_Ein[i] = ldin(E, i, g_flag[0]);
}
__global__ void k_castsrc(const void* __restrict__ src) {
  const int i = blockIdx.x*256 + threadIdx.x;
  if (i < B_*T_*N_) g_srcf[i] = ldin(src, i, g_flag[0]);
}
__global__ void k_castc(const void* __restrict__ cw, const void* __restrict__ cb) {
  const int i = blockIdx.x*256 + threadIdx.x;
  const int f = g_flag[0];
  if (i < HOR_*HID_) g_cwf[i] = ldin(cw, i, f);
  if (i < HOR_)      g_cbf[i] = ldin(cb, i, f);
}

// ---------------------------------------------------------------------------
// S = softmax(relu(Ein @ Ein^T), axis=1) -> hi/lo bf16 pair directly.
// ---------------------------------------------------------------------------
__global__ __launch_bounds__(256) void k_softmax_S() {
  bf16* Sh = (bf16*)g_Shi;
  bf16* Sl = (bf16*)g_Slo;
  const int n = blockIdx.x, tid = threadIdx.x;
  __shared__ float er[ED_];
  __shared__ float red[4];
  if (tid < ED_) er[tid] = g_Ein[n*ED_ + tid];
  __syncthreads();
  float e[ED_];
#pragma unroll
  for (int d = 0; d < ED_; ++d) e[d] = er[d];
  float v[8];
  float mx = 0.f;
#pragma unroll
  for (int j = 0; j < 8; ++j) {
    const int m = tid + j*256;
    float dot = 0.f;
#pragma unroll
    for (int d = 0; d < ED_; ++d) dot += e[d]*g_Ein[m*ED_ + d];
    v[j] = fmaxf(dot, 0.f);
    mx = fmaxf(mx, v[j]);
  }
  for (int o = 32; o; o >>= 1) mx = fmaxf(mx, __shfl_xor(mx, o, 64));
  if ((tid & 63) == 0) red[tid >> 6] = mx;
  __syncthreads();
  mx = fmaxf(fmaxf(red[0], red[1]), fmaxf(red[2], red[3]));
  __syncthreads();
  float sum = 0.f;
#pragma unroll
  for (int j = 0; j < 8; ++j) { v[j] = __expf(v[j] - mx); sum += v[j]; }
  for (int o = 32; o; o >>= 1) sum += __shfl_xor(sum, o, 64);
  if ((tid & 63) == 0) red[tid >> 6] = sum;
  __syncthreads();
  sum = red[0] + red[1] + red[2] + red[3];
  const float inv = 1.f / sum;
#pragma unroll
  for (int j = 0; j < 8; ++j) {
    const float sv = v[j]*inv;
    const size_t idx = (size_t)n*N_ + tid + j*256;
    const bf16 h = f2b(sv);
    Sh[idx] = h;
    Sl[idx] = f2b(sv - b2f(h));
  }
}

// split srcf -> hi/lo bf16 pair
__global__ void k_splitSrc() {
  const int i = blockIdx.x*256 + threadIdx.x;
  if (i < BT*N_) {
    const float v = g_srcf[i];
    const bf16 h = f2b(v);
    ((bf16*)g_srcHi)[i] = h;
    ((bf16*)g_srcLo)[i] = f2b(v - b2f(h));
  }
}

// ---------------------------------------------------------------------------
// Tiled transpose+split: X[n][BH] fp32 -> Th[c][N_], Tl[c][N_] bf16.
// xsel: 0=h0, 1=h2, 2=zh. dsel: 0=tmpT, 1=h2T.
// ---------------------------------------------------------------------------
__global__ __launch_bounds__(256) void k_trsp(int xsel, int dsel) {
  const float* X = (xsel == 0) ? g_h : (xsel == 1) ? (g_h + SL_) : g_zh;
  bf16* Th = (bf16*)((dsel == 0) ? g_tmpTh : g_h2Th);
  bf16* Tl = (bf16*)((dsel == 0) ? g_tmpTl : g_h2Tl);
  const int n0 = blockIdx.x * 64;
  const int c0 = blockIdx.y * 64;
  __shared__ float t[64][68];
  const int tid = threadIdx.x;
  {
    const int r = tid >> 2, q4 = (tid & 3) * 16;
    const float4* src = (const float4*)(X + (size_t)(n0 + r)*BH + c0 + q4);
#pragma unroll
    for (int u = 0; u < 4; ++u)
      *(float4*)&t[r][q4 + u*4] = src[u];
  }
  __syncthreads();
  {
    const int c = tid >> 2, sg = (tid & 3) * 16;
    bf16 hb[16], lb[16];
#pragma unroll
    for (int i = 0; i < 16; ++i) {
      const float v = t[sg + i][c];
      const bf16 h = f2b(v);
      hb[i] = h;
      lb[i] = f2b(v - b2f(h));
    }
    bf16* dh = Th + (size_t)(c0 + c)*N_ + n0 + sg;
    bf16* dl = Tl + (size_t)(c0 + c)*N_ + n0 + sg;
    *(uint4*)dh       = *(uint4*)&hb[0];
    *(uint4*)(dh + 8) = *(uint4*)&hb[8];
    *(uint4*)dl       = *(uint4*)&lb[0];
    *(uint4*)(dl + 8) = *(uint4*)&lb[8];
  }
}

// ---------------------------------------------------------------------------
// Basis weights -> PACKED d-interleaved layout, fp32 + bf16.
// wsel: 0=Wg0, 1=Wu0, 2=Wg1, 3=Wu1.
// ---------------------------------------------------------------------------
template<int LAYER>
__global__ __launch_bounds__(256) void k_prepP(const void* __restrict__ Wb,
                                               int KIin, int KIP, int O,
                                               int wsel) {
  float* PF = (wsel == 0) ? g_Wg0F : (wsel == 1) ? g_Wu0F
            : (wsel == 2) ? g_Wg1F : g_Wu1F;
  bf16* PH = (bf16*)((wsel == 0) ? g_Wg0H : (wsel == 1) ? g_Wu0H
            : (wsel == 2) ? g_Wg1H : g_Wu1H);
  const int idx = blockIdx.x*256 + threadIdx.x;
  if (idx >= ED_*O*KIP) return;
  const int d = idx / (O*KIP), rem = idx - d*O*KIP;
  const int o = rem / KIP, kp = rem - o*KIP;
  int cheb, i; bool valid;
  if (LAYER == 0) {
    cheb = (kp >= 80) ? 1 : 0;
    const int local = kp - cheb*80;
    if (local < 64)       { i = local + 1; valid = true; }
    else if (local == 64) { i = 0;         valid = true; }
    else                  { i = 0;         valid = false; }
  } else {
    cheb = kp >> 7; i = kp & 127; valid = true;
  }
  float v = 0.f;
  if (valid) v = ldin(Wb, (size_t)((d*2 + cheb)*KIin + i)*O + o, g_flag[0]);
  const int kg = kp >> 2, e = kp & 3;
  const size_t pi = ((size_t)(o*(KIP/4) + kg)*ED_ + d)*4 + e;
  PF[pi] = v;
  PH[pi] = f2b(v);
}

// bias vectors: outv[n][o] = sum_d Ein[n,d]*bb[d][o]
__global__ __launch_bounds__(128) void k_matb(const void* __restrict__ bb,
                                              int O, int osel) {
  float* outv = (osel == 0) ? g_bgv0 : (osel == 1) ? g_buv0
              : (osel == 2) ? g_bgv1 : g_buv1;
  const int n = blockIdx.x, tid = threadIdx.x;
  if (tid >= O) return;
  const int f = g_flag[0];
  float acc = 0.f;
#pragma unroll
  for (int d = 0; d < ED_; ++d) acc += g_Ein[n*ED_ + d]*ldin(bb, d*O + tid, f);
  outv[n*O + tid] = acc;
}

// Packed merge (single-n; R13 arithmetic)
template<int KIP>
__device__ __forceinline__ float4 merge_p(const float* __restrict__ PF,
                                          const bf16* __restrict__ PH,
                                          const float* el, int o, int kg,
                                          int isbf) {
  float4 a4 = make_float4(0.f, 0.f, 0.f, 0.f);
  const size_t gbase = (size_t)(o*(KIP/4) + kg)*(ED_*4);
  if (isbf) {
    const uint4* g = (const uint4*)(PH + gbase);
#pragma unroll
    for (int i = 0; i < 5; ++i) {
      const uint4 w = g[i];
      const float e0 = el[2*i], e1 = el[2*i + 1];
      a4.x += e0*bits2f(w.x & 0xFFFFu); a4.y += e0*bits2f(w.x >> 16);
      a4.z += e0*bits2f(w.y & 0xFFFFu); a4.w += e0*bits2f(w.y >> 16);
      a4.x += e1*bits2f(w.z & 0xFFFFu); a4.y += e1*bits2f(w.z >> 16);
      a4.z += e1*bits2f(w.w & 0xFFFFu); a4.w += e1*bits2f(w.w >> 16);
    }
  } else {
    const float4* g = (const float4*)(PF + gbase);
#pragma unroll
    for (int d = 0; d < ED_; ++d)
      fma4(a4, el[d], g[d]);
  }
  return a4;
}

// ---------------------------------------------------------------------------
// One-time merged-weight build. WM[n][o][k] (k contiguous), fp32.
// wsel: 0=Wg0M, 1=Wu0M, 2=Wg1M, 3=Wu1M.
// ---------------------------------------------------------------------------
template<int KIP>
__global__ __launch_bounds__(256) void k_merge(int O, int wsel) {
  const float* PF = (wsel == 0) ? g_Wg0F : (wsel == 1) ? g_Wu0F
                  : (wsel == 2) ? g_Wg1F : g_Wu1F;
  const bf16* PH = (const bf16*)((wsel == 0) ? g_Wg0H : (wsel == 1) ? g_Wu0H
                  : (wsel == 2) ? g_Wg1H : g_Wu1H);
  float* WM = (wsel == 0) ? g_Wg0M : (wsel == 1) ? g_Wu0M
            : (wsel == 2) ? g_Wg1M : g_Wu1M;
  const int n = blockIdx.x;
  const int idx = blockIdx.y*256 + threadIdx.x;
  __shared__ float es[ED_];
  if (threadIdx.x < ED_) es[threadIdx.x] = g_Ein[n*ED_ + threadIdx.x];
  __syncthreads();
  if (idx >= O*(KIP/4)) return;
  const int o = idx / (KIP/4), kg = idx - o*(KIP/4);
  float el[ED_];
#pragma unroll
  for (int d = 0; d < ED_; ++d) el[d] = es[d];
  const float4 a4 = merge_p<KIP>(PF, PH, el, o, kg, g_flag[0]);
  *(float4*)&WM[((size_t)n*O + o)*KIP + kg*4] = a4;
}

// ---------------------------------------------------------------------------
// Split-bf16 MFMA GEMM (R19): C(n,c) = sum_m S[n,m]*X[m,c]. 128x64 tile.
// xsel: 0=tmpT, 1=h2T, 2=srcT. csel: 0=Sh_a, 1=Sh_b, 2=Sx0.
// ---------------------------------------------------------------------------
__global__ __launch_bounds__(256) void k_gemmM(int x1, int c1, int ldc1,
                                               int x2, int c2, int ldc2,
                                               int split) {
  const bf16* Sh = (const bf16*)g_Shi;
  const bf16* Sl = (const bf16*)g_Slo;
  const int bm = blockIdx.x * 128;
  int bc = blockIdx.y * 64;
  int xs = x1, cs = c1, ldc = ldc1;
  if (bc >= split) { xs = x2; cs = c2; ldc = ldc2; bc -= split; }
  const bf16* Xh = (const bf16*)((xs == 0) ? g_tmpTh : (xs == 1) ? g_h2Th : g_srcHi);
  const bf16* Xl = (const bf16*)((xs == 0) ? g_tmpTl : (xs == 1) ? g_h2Tl : g_srcLo);
  float* C = (cs == 0) ? g_Sh : (cs == 1) ? (g_Sh + SL_) : g_Sx0;

  __shared__ __align__(16) bf16 Ah[128][72];
  __shared__ __align__(16) bf16 Al[128][72];
  __shared__ __align__(16) bf16 Bh[64][72];
  __shared__ __align__(16) bf16 Bl[64][72];
  const int tid = threadIdx.x;
  const int wave = tid >> 6, lane = tid & 63, q = lane >> 4, ln = lane & 15;
  const int wm = wave >> 1, wn = wave & 1;
  const int srow = tid >> 3, scol = (tid & 7) * 8;

  floatx4 acc[4][2];
#pragma unroll
  for (int mt = 0; mt < 4; ++mt)
#pragma unroll
    for (int nt = 0; nt < 2; ++nt) acc[mt][nt] = (floatx4){0.f,0.f,0.f,0.f};

  for (int mk = 0; mk < N_; mk += 64) {
#pragma unroll
    for (int i = 0; i < 4; ++i) {
      const int r = i*32 + srow;
      *(uint4*)&Ah[r][scol] = *(const uint4*)(Sh + (size_t)(bm + r)*N_ + mk + scol);
      *(uint4*)&Al[r][scol] = *(const uint4*)(Sl + (size_t)(bm + r)*N_ + mk + scol);
    }
#pragma unroll
    for (int i = 0; i < 2; ++i) {
      const int r = i*32 + srow;
      *(uint4*)&Bh[r][scol] = *(const uint4*)(Xh + (size_t)(bc + r)*N_ + mk + scol);
      *(uint4*)&Bl[r][scol] = *(const uint4*)(Xl + (size_t)(bc + r)*N_ + mk + scol);
    }
    __syncthreads();
#pragma unroll
    for (int ks = 0; ks < 64; ks += 32) {
      short8 ah[4], al[4], bh[2], bl[2];
#pragma unroll
      for (int mt = 0; mt < 4; ++mt) {
        ah[mt] = *(const short8*)&Ah[wm*64 + mt*16 + ln][ks + q*8];
        al[mt] = *(const short8*)&Al[wm*64 + mt*16 + ln][ks + q*8];
      }
#pragma unroll
      for (int nt = 0; nt < 2; ++nt) {
        bh[nt] = *(const short8*)&Bh[wn*32 + nt*16 + ln][ks + q*8];
        bl[nt] = *(const short8*)&Bl[wn*32 + nt*16 + ln][ks + q*8];
      }
#pragma unroll
      for (int mt = 0; mt < 4; ++mt)
#pragma unroll
        for (int nt = 0; nt < 2; ++nt) {
          acc[mt][nt] = __builtin_amdgcn_mfma_f32_16x16x32_bf16(ah[mt], bh[nt], acc[mt][nt], 0, 0, 0);
          acc[mt][nt] = __builtin_amdgcn_mfma_f32_16x16x32_bf16(al[mt], bh[nt], acc[mt][nt], 0, 0, 0);
          acc[mt][nt] = __builtin_amdgcn_mfma_f32_16x16x32_bf16(ah[mt], bl[nt], acc[mt][nt], 0, 0, 0);
        }
    }
    __syncthreads();
  }
#pragma unroll
  for (int mt = 0; mt < 4; ++mt)
#pragma unroll
    for (int nt = 0; nt < 2; ++nt)
#pragma unroll
      for (int r = 0; r < 4; ++r)
        C[(size_t)(bm + wm*64 + mt*16 + q*4 + r)*ldc + bc + wn*32 + nt*16 + ln] =
            acc[mt][nt][r];
}

// ---------------------------------------------------------------------------
// xg builder (float4): xg[b][k], padded row stride KIPP (R13 verbatim).
// ---------------------------------------------------------------------------
template<int LAYER, int KIP, int KIPP>
__device__ __forceinline__ void build4(float (*xg)[KIPP],
                                       const float* p0, const float* p1,
                                       const float* p2, const float* p3,
                                       int n, int t, int tid) {
  constexpr int NQ = KIP/4;
  for (int idx = tid; idx < B_*NQ; idx += 256) {
    const int b = idx / NQ, k = (idx - b*NQ) * 4;
    float4 v = make_float4(0.f, 0.f, 0.f, 0.f);
    if (LAYER == 1) {
      const float* rg = (k < 64) ? p0 : (k < 128) ? p1 : (k < 192) ? p2 : p3;
      v = *(const float4*)(rg + (size_t)n*BH + b*64 + (k & 63));
    } else {
      if (k < 64)        v = *(const float4*)(p0 + (size_t)n*BH + b*64 + k);
      else if (k == 64)  v.x = p1[(size_t)(b*T_ + t)*N_ + n];
      else if (k >= 80 && k < 144)
                         v = *(const float4*)(p2 + (size_t)n*BH + b*64 + (k - 80));
      else if (k == 144) v.x = p3[(size_t)n*BT + b*T_ + t];
    }
    *(float4*)&xg[b][k] = v;
  }
}

// ---------------------------------------------------------------------------
// Gate premerged — stream WM[n] tiles (stage->sync->compute->sync).
// R32: launch_bounds (256,4) — pure-read stream, 4 blocks/CU.
// ---------------------------------------------------------------------------
template<int LAYER, int KIP>
__global__ __launch_bounds__(256, 4) void k_gateWpm(int t) {
  constexpr int KIPP = KIP + 4;
  constexpr int O = 128;
  const float* WM = (LAYER == 0) ? g_Wg0M : g_Wg1M;
  const float* bgv = (LAYER == 0) ? g_bgv0 : g_bgv1;
  const float* p0 = g_h;
  const float* p1 = (LAYER == 0) ? g_srcf : (g_h + SL_);
  const float* p2 = g_Sh;
  const float* p3 = (LAYER == 0) ? g_Sx0 : (g_Sh + SL_);
  const float* hstate = (LAYER == 0) ? g_h : (g_h + SL_);
  const int n = blockIdx.x, tid = threadIdx.x;
  __shared__ float xg[B_][KIPP];
  __shared__ float wm[O][36];
  build4<LAYER, KIP, KIPP>(xg, p0, p1, p2, p3, n, t, tid);

  const float* WMn = WM + (size_t)n*O*KIP;
  const int b = tid >> 4, q = tid & 15;
  float acc[8];
#pragma unroll
  for (int j = 0; j < 8; ++j) acc[j] = 0.f;

  for (int k0 = 0; k0 < KIP; k0 += 32) {
#pragma unroll
    for (int i = 0; i < O*8/256; ++i) {
      const int idx = tid + i*256;
      const int o = idx >> 3, kq = idx & 7;
      *(float4*)&wm[o][kq*4] =
          *(const float4*)(WMn + (size_t)o*KIP + k0 + kq*4);
    }
    __syncthreads();   // wm ready (and xg on first iter)
#pragma unroll
    for (int kq = 0; kq < 8; ++kq) {
      const float4 xv = *(const float4*)&xg[b][k0 + kq*4];
#pragma unroll
      for (int j = 0; j < 8; ++j) {
        const float4 wv = *(const float4*)&wm[q + 16*j][kq*4];
        acc[j] += xv.x*wv.x + xv.y*wv.y + xv.z*wv.z + xv.w*wv.w;
      }
    }
    __syncthreads();
  }
#pragma unroll
  for (int j = 0; j < 8; ++j) {
    const int o = q + 16*j;
    float s = acc[j] + bgv[n*128 + o];
    s = 1.f/(1.f + __expf(-s));
    if (o < HID_) {
      g_zh[(size_t)n*BH + b*64 + o] = s*hstate[(size_t)n*BH + b*64 + o];
    } else {
      g_rbuf[(size_t)n*BH + b*64 + (o - HID_)] = s;
    }
  }
}

// ---------------------------------------------------------------------------
// Candidate premerged — same stream structure (O=64).
// R32: launch_bounds (256,4).
// ---------------------------------------------------------------------------
template<int LAYER, int KIP>
__global__ __launch_bounds__(256, 4) void k_candWpm(int t) {
  constexpr int KIPP = KIP + 4;
  constexpr int O = 64;
  const float* WM = (LAYER == 0) ? g_Wu0M : g_Wu1M;
  const float* buv = (LAYER == 0) ? g_buv0 : g_buv1;
  const float* p0 = (LAYER == 0) ? g_zh : g_h;
  const float* p1 = (LAYER == 0) ? g_srcf : g_zh;
  const float* p2 = (LAYER == 0) ? (g_Sh + SL_) : g_Sh;
  const float* p3 = (LAYER == 0) ? g_Sx0 : (g_Sh + SL_);
  float* hstate = (LAYER == 0) ? g_h : (g_h + SL_);
  const int n = blockIdx.x, tid = threadIdx.x;
  __shared__ float xg[B_][KIPP];
  __shared__ float wm[O][36];
  build4<LAYER, KIP, KIPP>(xg, p0, p1, p2, p3, n, t, tid);

  const float* WMn = WM + (size_t)n*O*KIP;
  const int b = tid >> 4, q = tid & 15;
  float acc[4];
#pragma unroll
  for (int j = 0; j < 4; ++j) acc[j] = 0.f;

  for (int k0 = 0; k0 < KIP; k0 += 32) {
#pragma unroll
    for (int i = 0; i < O*8/256; ++i) {
      const int idx = tid + i*256;
      const int o = idx >> 3, kq = idx & 7;
      *(float4*)&wm[o][kq*4] =
          *(const float4*)(WMn + (size_t)o*KIP + k0 + kq*4);
    }
    __syncthreads();
#pragma unroll
    for (int kq = 0; kq < 8; ++kq) {
      const float4 xv = *(const float4*)&xg[b][k0 + kq*4];
#pragma unroll
      for (int j = 0; j < 4; ++j) {
        const float4 wv = *(const float4*)&wm[q + 16*j][kq*4];
        acc[j] += xv.x*wv.x + xv.y*wv.y + xv.z*wv.z + xv.w*wv.w;
      }
    }
    __syncthreads();
  }
#pragma unroll
  for (int j = 0; j < 4; ++j) {
    const int o = q + 16*j;
    const float hc = tanhf(acc[j] + buv[n*64 + o]);
    const float rr = g_rbuf[(size_t)n*BH + b*64 + o];
    const float hold = hstate[(size_t)n*BH + b*64 + o];
    hstate[(size_t)n*BH + b*64 + o] = rr*hold + (1.f - rr)*hc;
  }
}

// sel: 0 = zero g_h[0..2SL), 1 = zero g_Sh[0..2SL)
__global__ void k_zero_f(int sel) {
  float* p = (sel == 0) ? g_h : g_Sh;
  const int i = blockIdx.x*256 + threadIdx.x;
  if (i < 2*SL_) p[i] = 0.f;
}

// out[b][hor][n] = sum_c h2[n][b*64+c]*cwf[hor][c] + cbf[hor]
__global__ __launch_bounds__(256) void k_conv(void* __restrict__ out) {
  const float* h2 = g_h + SL_;
  const int n = blockIdx.x, tid = threadIdx.x;
  __shared__ float hs[BH];
  for (int i = tid; i < BH; i += 256) hs[i] = h2[(size_t)n*BH + i];
  __syncthreads();
  const int isbf = g_flag[0];
  for (int i = tid; i < B_*HOR_; i += 256) {
    const int b = i / HOR_, hor = i - b*HOR_;
    float acc = g_cbf[hor];
#pragma unroll
    for (int c = 0; c < HID_; ++c) acc += hs[b*HID_ + c]*g_cwf[hor*HID_ + c];
    const size_t oi = (size_t)(b*HOR_ + hor)*N_ + n;
    if (isbf) ((bf16*)out)[oi] = f2b(acc);
    else      ((float*)out)[oi] = acc;
  }
}

// ---------------------------------------------------------------------------
extern "C" void kernel_launch(void* const* d_in, const int* in_sizes, int n_in,
                              void* d_out, int out_size, void* d_ws, size_t ws_size,
                              hipStream_t stream) {
  (void)out_size; (void)d_ws; (void)ws_size;

  // --- identify inputs by element count (robust to reordering). ---
  static const long long cnt[12] = {
    393216, 20480, 166400, 1280, 83200, 640,
    327680, 1280, 163840, 640, 768, 12
  };
  const void* in[12];
  bool ok = (n_in == 12) && (in_sizes != nullptr) && (d_in != nullptr);
  if (ok) {
    long long mx = 0;
    for (int i = 0; i < 12; ++i) if ((long long)in_sizes[i] > mx) mx = in_sizes[i];
    long long scale = mx / 393216LL;
    if (scale != 1 && scale != 2 && scale != 4) ok = false;
    if (ok && scale*393216LL != mx) ok = false;
    bool used[12] = {false,false,false,false,false,false,false,false,false,false,false,false};
    for (int k = 0; k < 12 && ok; ++k) {
      int found = -1;
      for (int i = 0; i < 12; ++i)
        if (!used[i] && (long long)in_sizes[i] == cnt[k]*scale) { found = i; break; }
      if (found < 0) ok = false;
      else { used[found] = true; in[k] = d_in[found]; }
    }
  }
  if (!ok) for (int k = 0; k < 12; ++k) in[k] = d_in[k];

  const void* src = in[0];
  const void* E   = in[1];
  const void* Wg0 = in[2];
  const void* bg0 = in[3];
  const void* Wu0 = in[4];
  const void* bu0 = in[5];
  const void* Wg1 = in[6];
  const void* bg1 = in[7];
  const void* Wu1 = in[8];
  const void* bu1 = in[9];
  const void* cw  = in[10];
  const void* cb  = in[11];

  auto cdiv = [](int a, int b) { return (a + b - 1) / b; };

  k_detect<<<dim3(1), 256, 0, stream>>>(E);

  // --- casts + setup ---
  k_castE  <<<dim3(cdiv(N_*ED_, 256)), 256, 0, stream>>>(E);
  k_castsrc<<<dim3(cdiv(BT*N_, 256)),  256, 0, stream>>>(src);
  k_castc  <<<dim3(cdiv(HOR_*HID_, 256)), 256, 0, stream>>>(cw, cb);
  k_prepP<0><<<dim3(cdiv(ED_*128*160, 256)), 256, 0, stream>>>(Wg0, 65, 160, 128, 0);
  k_prepP<0><<<dim3(cdiv(ED_*64*160,  256)), 256, 0, stream>>>(Wu0, 65, 160, 64, 1);
  k_prepP<1><<<dim3(cdiv(ED_*128*256, 256)), 256, 0, stream>>>(Wg1, 128, 256, 128, 2);
  k_prepP<1><<<dim3(cdiv(ED_*64*256,  256)), 256, 0, stream>>>(Wu1, 128, 256, 64, 3);
  k_matb<<<dim3(N_), 128, 0, stream>>>(bg0, 128, 0);
  k_matb<<<dim3(N_), 128, 0, stream>>>(bu0, 64,  1);
  k_matb<<<dim3(N_), 128, 0, stream>>>(bg1, 128, 2);
  k_matb<<<dim3(N_), 128, 0, stream>>>(bu1, 64,  3);
  k_softmax_S<<<dim3(N_), 256, 0, stream>>>();
  k_splitSrc<<<dim3(cdiv(BT*N_, 256)), 256, 0, stream>>>();

  // --- one-time merged weights (all four tiers) ---
  k_merge<160><<<dim3(N_, 20), 256, 0, stream>>>(128, 0);   // Wg0M
  k_merge<160><<<dim3(N_, 10), 256, 0, stream>>>(64,  1);   // Wu0M
  k_merge<256><<<dim3(N_, 32), 256, 0, stream>>>(128, 2);   // Wg1M
  k_merge<256><<<dim3(N_, 16), 256, 0, stream>>>(64,  3);   // Wu1M

  // Sx0[n, bt] = sum_m S[n,m]*srcf[bt*N + m]  (split-bf16 MFMA gemm)
  k_gemmM<<<dim3(N_/128, BT/64), 256, 0, stream>>>(2, 2, BT, 2, 2, BT, 1 << 30);

  // zero recurrent states (h0|h2) + Sh_a|Sh_b
  k_zero_f<<<dim3((2*SL_ + 255)/256), 256, 0, stream>>>(0);
  k_zero_f<<<dim3((2*SL_ + 255)/256), 256, 0, stream>>>(1);

  // --- t = 0 (states zero: all Sh terms vanish except S@h1[0]) ---
  k_gateWpm<0,160><<<dim3(N_), 256, 0, stream>>>(0);
  k_candWpm<0,160><<<dim3(N_), 256, 0, stream>>>(0);
  k_trsp<<<dim3(N_/64, BH/64), 256, 0, stream>>>(0, 0);           // h0 -> tmpT
  k_gemmM<<<dim3(N_/128, BH/64), 256, 0, stream>>>(0, 0, BH, 0, 0, BH, 1 << 30); // Sh_a = S@h1[0]
  k_gateWpm<1,256><<<dim3(N_), 256, 0, stream>>>(0);
  k_candWpm<1,256><<<dim3(N_), 256, 0, stream>>>(0);
  k_trsp<<<dim3(N_/64, BH/64), 256, 0, stream>>>(1, 1);           // h2 -> h2T

  // --- t >= 1 ---
  for (int t = 1; t < T_; ++t) {
    k_gateWpm<0,160><<<dim3(N_), 256, 0, stream>>>(t);
    k_trsp<<<dim3(N_/64, BH/64), 256, 0, stream>>>(2, 0);         // zh -> tmpT
    k_gemmM<<<dim3(N_/128, BH/64), 256, 0, stream>>>(0, 1, BH, 0, 1, BH, 1 << 30); // Sh_b = S@zh0
    k_candWpm<0,160><<<dim3(N_), 256, 0, stream>>>(t);
    k_trsp<<<dim3(N_/64, BH/64), 256, 0, stream>>>(0, 0);         // h0 -> tmpT
    // dual: Sh_a = S@h1t, Sh_b = S@h2
    k_gemmM<<<dim3(N_/128, 2*BH/64), 256, 0, stream>>>(0, 0, BH, 1, 1, BH, BH);
    k_gateWpm<1,256><<<dim3(N_), 256, 0, stream>>>(t);
    k_trsp<<<dim3(N_/64, BH/64), 256, 0, stream>>>(2, 0);         // zh -> tmpT
    k_gemmM<<<dim3(N_/128, BH/64), 256, 0, stream>>>(0, 1, BH, 0, 1, BH, 1 << 30); // Sh_b = S@zh1
    k_candWpm<1,256><<<dim3(N_), 256, 0, stream>>>(t);
    k_trsp<<<dim3(N_/64, BH/64), 256, 0, stream>>>(1, 1);         // h2 -> h2T
  }

  // --- final conv ---
  k_conv<<<dim3(N_), 256, 0, stream>>>(d_out);
}